// Round 3
// baseline (13955.797 us; speedup 1.0000x reference)
//
#include <hip/hip_runtime.h>
#include <stdint.h>

namespace {
constexpr int kB = 64, kT = 200;
constexpr int kNin = 700, kNs = 50, kNz = 100, kNh = 512, kNho = 100, kNout = 20;
constexpr float kDecay = 0.95f, kThresh = 0.5f, kRefrac = 2.0f;
}

// Adaptive-LIF update (REST=RESET=0, DT=1).
__device__ __forceinline__ void lif(float& v, float& r, float x, bool& spk) {
    r = fmaxf(r - 1.0f, 0.0f);
    v = kDecay * v + (r <= 0.0f ? x : 0.0f);
    spk = (v >= kThresh);
    if (spk) { v = 0.0f; r = kRefrac; }
}

// Deterministic sparse row-sum: sum_{i in lst[0..cnt)} W[i*ld + j]
__device__ __forceinline__ float rowsum(const unsigned short* lst, int cnt,
                                        const float* __restrict__ W, int ld, int j) {
    float a0 = 0.f, a1 = 0.f, a2 = 0.f, a3 = 0.f;
    int q = 0;
    for (; q + 4 <= cnt; q += 4) {
        const int i0 = lst[q], i1 = lst[q + 1], i2 = lst[q + 2], i3 = lst[q + 3];
        a0 += W[i0 * ld + j];
        a1 += W[i1 * ld + j];
        a2 += W[i2 * ld + j];
        a3 += W[i3 * ld + j];
    }
    for (; q < cnt; ++q) a0 += W[lst[q] * ld + j];
    return (a0 + a1) + (a2 + a3);
}

__global__ __launch_bounds__(1024, 4)
void snn_seq(const float* __restrict__ x_in, const float* __restrict__ W_i,
             const float* __restrict__ W_z, const float* __restrict__ W_c,
             const float* __restrict__ W_h, const float* __restrict__ W_ho,
             const float* __restrict__ W_o, const float* __restrict__ lam_p,
             const float* __restrict__ eta_p, float* __restrict__ out) {
    __shared__ unsigned long long hist[kT][8];          // 12800 B: h spike history
    __shared__ float xi[kT * kNs];                      // 40000 B: precomputed x@W_i
    __shared__ float lampow[kT];                        // 800
    __shared__ float ck[kT];                            // 800
    __shared__ __align__(16) float prevh[kNh];          // 2048: h_new state
    __shared__ float fpart[kNh];                        // 2048: dense-matvec K-half partial
    __shared__ float hpart[kNh];                        // 2048: recall/rowsum partial
    __shared__ float ho_red[8][kNho];                   // 3200: h_new@W_ho partials
    __shared__ unsigned short idx_s[kNs], idx_z[kNz], idx_h[kNh], idx_o[kNho];
    __shared__ int cnt_z, cnt_h;

    const int tid = threadIdx.x;
    const int lane = tid & 63;
    const int wave = tid >> 6;
    const int q = tid >> 9;        // K-half / role split
    const int j = tid & 511;       // neuron index within h population
    const int b = blockIdx.x;
    const float lam = lam_p[0], eta = eta_p[0];

    // ---- prologue: lampow, prevh=0, xi = x@W_i for all t (register-tiled) ----
    if (tid == 0) {
        float p = 1.0f;
        for (int i = 0; i < kT; ++i) { lampow[i] = p; p *= lam; }
    }
    if (tid < kNh) prevh[tid] = 0.0f;
    if (tid < 1000) {
        const int jj = tid % kNs;          // output col 0..49
        const int tslot = tid / kNs;       // 0..19
        const float* wcol = W_i + jj;
        const size_t stride20 = (size_t)20 * kB * kNin;
        // two passes of 5 time-streams each (bounded register pressure)
        for (int pass = 0; pass < 2; ++pass) {
            const float* x0 = x_in + ((size_t)tslot * kB + b) * kNin +
                              (size_t)pass * 5 * stride20;
            float a0 = 0, a1 = 0, a2 = 0, a3 = 0, a4 = 0;
            for (int i = 0; i < kNin; ++i) {
                const float w = wcol[i * kNs];
                a0 = fmaf(x0[i], w, a0);
                a1 = fmaf(x0[stride20 + i], w, a1);
                a2 = fmaf(x0[2 * stride20 + i], w, a2);
                a3 = fmaf(x0[3 * stride20 + i], w, a3);
                a4 = fmaf(x0[4 * stride20 + i], w, a4);
            }
            const int tb = tslot + pass * 100;
            xi[(tb + 0) * kNs + jj] = a0;
            xi[(tb + 20) * kNs + jj] = a1;
            xi[(tb + 40) * kNs + jj] = a2;
            xi[(tb + 60) * kNs + jj] = a3;
            xi[(tb + 80) * kNs + jj] = a4;
        }
    }

    // LIF states (live only in owner lanes)
    float vs = 0, rs = 0;                         // wave 15, lane<50
    float vz0 = 0, rz0 = 0, vz1 = 0, rz1 = 0;     // wave 15
    float vh = 0, rh = 0;                         // q==0 (thread j)
    float vo0 = 0, ro0 = 0, vo1 = 0, ro1 = 0;     // wave 0
    float vy = 0, ry = 0;                         // wave 0, lane<20
    float czv = 0, facc = 0, hreg = 0;

    __syncthreads();

    for (int t = 0; t < kT; ++t) {
        // ---- S7 (wave 0): o-LIF + y-LIF epilogue of step t-1 (overlaps F) ----
        if (wave == 0 && t > 0) {
            float oa0 = 0, oa1 = 0;
#pragma unroll
            for (int g = 0; g < 8; ++g) {
                oa0 += ho_red[g][lane];
                if (lane < 36) oa1 += ho_red[g][64 + lane];
            }
            bool o0 = false, o1 = false;
            lif(vo0, ro0, oa0, o0);
            if (lane < 36) lif(vo1, ro1, oa1, o1);
            const unsigned long long om0 = __ballot(o0);
            const unsigned long long om1 = __ballot(o1);
            if (o0) idx_o[__popcll(om0 & ((1ull << lane) - 1))] = (unsigned short)lane;
            if (o1) idx_o[__popcll(om0) + __popcll(om1 & ((1ull << lane) - 1))] =
                (unsigned short)(64 + lane);
            const int co = __popcll(om0) + __popcll(om1);
            if (lane < kNout) {
                const float yx = rowsum(idx_o, co, W_o, kNout, lane);
                bool ys = false;
                lif(vy, ry, yx, ys);
                out[((size_t)(t - 1) * kB + b) * kNout + lane] = ys ? 1.0f : 0.0f;
            }
        }
        // ---- S1 (wave 15): s-LIF + z-LIF + index lists (overlaps F) ----
        if (wave == 15) {
            bool sspk = false;
            if (lane < kNs) {
                const float sx = xi[t * kNs + lane];
                lif(vs, rs, sx, sspk);
            }
            const unsigned long long sm = __ballot(sspk);
            if (sspk) idx_s[__popcll(sm & ((1ull << lane) - 1))] = (unsigned short)lane;
            const int cs = __popcll(sm);
            bool z0 = false, z1 = false;
            const float zx0 = rowsum(idx_s, cs, W_z, kNz, lane);
            lif(vz0, rz0, zx0, z0);
            if (lane < 36) {
                const float zx1 = rowsum(idx_s, cs, W_z, kNz, 64 + lane);
                lif(vz1, rz1, zx1, z1);
            }
            const unsigned long long zm0 = __ballot(z0);
            const unsigned long long zm1 = __ballot(z1);
            if (z0) idx_z[__popcll(zm0 & ((1ull << lane) - 1))] = (unsigned short)lane;
            if (z1) idx_z[__popcll(zm0) + __popcll(zm1 & ((1ull << lane) - 1))] =
                (unsigned short)(64 + lane);
            if (lane == 0) cnt_z = __popcll(zm0) + __popcll(zm1);
        }
        // ---- F (all): dense prevh @ W_h, split-K halves of 256 ----
        {
            const float* wh = W_h + j;
            const int k0 = q << 8;
            float a0 = 0.f, a1 = 0.f, a2 = 0.f, a3 = 0.f;
            for (int k = k0; k < k0 + 256; k += 8) {
                const float4 p0 = *(const float4*)&prevh[k];
                const float4 p1 = *(const float4*)&prevh[k + 4];
                a0 = fmaf(p0.x, wh[(k + 0) * kNh], a0);
                a1 = fmaf(p0.y, wh[(k + 1) * kNh], a1);
                a2 = fmaf(p0.z, wh[(k + 2) * kNh], a2);
                a3 = fmaf(p0.w, wh[(k + 3) * kNh], a3);
                a0 = fmaf(p1.x, wh[(k + 4) * kNh], a0);
                a1 = fmaf(p1.y, wh[(k + 5) * kNh], a1);
                a2 = fmaf(p1.z, wh[(k + 6) * kNh], a2);
                a3 = fmaf(p1.w, wh[(k + 7) * kNh], a3);
            }
            facc = (a0 + a1) + (a2 + a3);
            if (q) fpart[j] = facc;
        }
        __syncthreads();  // bar1

        // ---- S2 (q==0): cz rowsum + combine + h-LIF + history ballot ----
        bool hspk = false;
        if (q == 0) {
            czv = rowsum(idx_z, cnt_z, W_c, kNh, j);
            const float tot = facc + fpart[j] + czv;
            lif(vh, rh, tot, hspk);
        }
        {
            const unsigned long long hm = __ballot(hspk);
            if (q == 0 && lane == 0) hist[t][wave] = hm;
        }
        __syncthreads();  // bar2

        // ---- S3: recall coefficients ck + h index list ----
        if (tid <= t) {
            const unsigned long long* ht = hist[t];
            const unsigned long long* hk = hist[tid];
            int d = 0;
#pragma unroll
            for (int w = 0; w < 8; ++w) d += __popcll(ht[w] & hk[w]);
            ck[tid] = eta * lampow[t - tid] * (float)d;
        }
        if (q == 0) {
            const unsigned long long mw = hist[t][wave];
            if ((mw >> lane) & 1) {
                int pos = __popcll(mw & ((1ull << lane) - 1));
                for (int u = 0; u < wave; ++u) pos += __popcll(hist[t][u]);
                idx_h[pos] = (unsigned short)j;
            }
            if (tid == 0) {
                int c = 0;
#pragma unroll
                for (int u = 0; u < 8; ++u) c += __popcll(hist[t][u]);
                cnt_h = c;
            }
        }
        __syncthreads();  // bar3

        // ---- S4 (all): split sparse h@W_h rowsum + split recall loop ----
        {
            const int ch = cnt_h;
            const int ch2 = ch >> 1;
            const int half = (t + 1) >> 1;
            const int rlo = q ? ch2 : 0;
            const int rn = q ? (ch - ch2) : ch2;
            const int klo = q ? half : 0;
            const int khi = q ? (t + 1) : half;
            float part = rowsum(idx_h + rlo, rn, W_h, kNh, j);
            const int w = j >> 6, bit = j & 63;
            float racc = 0.f;
            for (int k = klo; k < khi; ++k) {
                const float c = ck[k];
                racc += ((hist[k][w] >> bit) & 1) ? c : 0.f;
            }
            part += racc;
            if (q) hpart[j] = part; else hreg = part;
        }
        __syncthreads();  // bar4

        // ---- S5 (q==0): h_new = hw + cz + recall ----
        if (q == 0) prevh[j] = hreg + hpart[j] + czv;
        __syncthreads();  // bar5

        // ---- S6: h_new @ W_ho partials (8 groups of 64 rows x 100 cols) ----
        if (tid < 800) {
            const int g = tid / kNho, j2 = tid - g * kNho;
            const float* wp = W_ho + j2;
            float s0 = 0.f, s1 = 0.f;
            const int i0 = g * 64;
            for (int i = i0; i < i0 + 64; i += 2) {
                s0 = fmaf(prevh[i], wp[i * kNho], s0);
                s1 = fmaf(prevh[i + 1], wp[(i + 1) * kNho], s1);
            }
            ho_red[g][j2] = s0 + s1;
        }
        __syncthreads();  // bar6
    }

    // ---- final epilogue for t = kT-1 ----
    if (wave == 0) {
        float oa0 = 0, oa1 = 0;
#pragma unroll
        for (int g = 0; g < 8; ++g) {
            oa0 += ho_red[g][lane];
            if (lane < 36) oa1 += ho_red[g][64 + lane];
        }
        bool o0 = false, o1 = false;
        lif(vo0, ro0, oa0, o0);
        if (lane < 36) lif(vo1, ro1, oa1, o1);
        const unsigned long long om0 = __ballot(o0);
        const unsigned long long om1 = __ballot(o1);
        if (o0) idx_o[__popcll(om0 & ((1ull << lane) - 1))] = (unsigned short)lane;
        if (o1) idx_o[__popcll(om0) + __popcll(om1 & ((1ull << lane) - 1))] =
            (unsigned short)(64 + lane);
        const int co = __popcll(om0) + __popcll(om1);
        if (lane < kNout) {
            const float yx = rowsum(idx_o, co, W_o, kNout, lane);
            bool ys = false;
            lif(vy, ry, yx, ys);
            out[((size_t)(kT - 1) * kB + b) * kNout + lane] = ys ? 1.0f : 0.0f;
        }
    }
}

extern "C" void kernel_launch(void* const* d_in, const int* in_sizes, int n_in,
                              void* d_out, int out_size, void* d_ws, size_t ws_size,
                              hipStream_t stream) {
    const float* x_in = (const float*)d_in[0];
    const float* W_i  = (const float*)d_in[1];
    const float* W_z  = (const float*)d_in[2];
    const float* W_c  = (const float*)d_in[3];
    const float* W_h  = (const float*)d_in[4];
    const float* W_ho = (const float*)d_in[5];
    const float* W_o  = (const float*)d_in[6];
    const float* lam  = (const float*)d_in[7];
    const float* eta  = (const float*)d_in[8];
    snn_seq<<<kB, 1024, 0, stream>>>(x_in, W_i, W_z, W_c, W_h, W_ho, W_o, lam, eta,
                                     (float*)d_out);
}

// Round 4
// 13954.466 us; speedup vs baseline: 1.0001x; 1.0001x over previous
//
#include <hip/hip_runtime.h>
#include <stdint.h>

namespace {
constexpr int kB = 64, kT = 200;
constexpr int kNin = 700, kNs = 50, kNz = 100, kNh = 512, kNho = 100, kNout = 20;
constexpr float kDecay = 0.95f, kThresh = 0.5f, kRefrac = 2.0f;
}

// Adaptive-LIF update (REST=RESET=0, DT=1).
__device__ __forceinline__ void lif(float& v, float& r, float x, bool& spk) {
    r = fmaxf(r - 1.0f, 0.0f);
    v = kDecay * v + (r <= 0.0f ? x : 0.0f);
    spk = (v >= kThresh);
    if (spk) { v = 0.0f; r = kRefrac; }
}

// Deterministic sparse row-sum: sum_{i in lst[0..cnt)} W[i*ld + j]
__device__ __forceinline__ float rowsum(const unsigned short* lst, int cnt,
                                        const float* __restrict__ W, int ld, int j) {
    float a0 = 0.f, a1 = 0.f, a2 = 0.f, a3 = 0.f;
    int q = 0;
    for (; q + 4 <= cnt; q += 4) {
        const int i0 = lst[q], i1 = lst[q + 1], i2 = lst[q + 2], i3 = lst[q + 3];
        a0 += W[i0 * ld + j];
        a1 += W[i1 * ld + j];
        a2 += W[i2 * ld + j];
        a3 += W[i3 * ld + j];
    }
    for (; q < cnt; ++q) a0 += W[lst[q] * ld + j];
    return (a0 + a1) + (a2 + a3);
}

__global__ __launch_bounds__(1024)
__attribute__((amdgpu_waves_per_eu(4, 4)))
void snn_seq(const float* __restrict__ x_in, const float* __restrict__ W_i,
             const float* __restrict__ W_z, const float* __restrict__ W_c,
             const float* __restrict__ W_h, const float* __restrict__ W_ho,
             const float* __restrict__ W_o, const float* __restrict__ lam_p,
             const float* __restrict__ eta_p, float* __restrict__ out) {
    __shared__ unsigned long long hist[kT][8];          // 12800 B: h spike history
    __shared__ float xi[kT * kNs];                      // 40000 B: precomputed x@W_i
    __shared__ float lampow[kT];                        // 800
    __shared__ float ck[kT];                            // 800
    __shared__ __align__(16) float prevh[kNh];          // 2048: h_new state
    __shared__ float fpart[kNh];                        // 2048: dense-matvec K-half partial
    __shared__ float hpart[kNh];                        // 2048: recall/rowsum partial
    __shared__ float ho_red[8][kNho];                   // 3200: h_new@W_ho partials
    __shared__ unsigned short idx_s[kNs], idx_z[kNz], idx_h[kNh], idx_o[kNho];
    __shared__ int cnt_z, cnt_h;

    const int tid = threadIdx.x;
    const int lane = tid & 63;
    const int wave = tid >> 6;
    const int q = tid >> 9;        // K-half / role split
    const int j = tid & 511;       // neuron index within h population
    const int b = blockIdx.x;
    const float lam = lam_p[0], eta = eta_p[0];

    // ---- prologue: lampow, prevh=0, xi = x@W_i for all t (register-tiled) ----
    if (tid == 0) {
        float p = 1.0f;
        for (int i = 0; i < kT; ++i) { lampow[i] = p; p *= lam; }
    }
    if (tid < kNh) prevh[tid] = 0.0f;
    if (tid < 1000) {
        const int jj = tid % kNs;          // output col 0..49
        const int tslot = tid / kNs;       // 0..19
        const float* wcol = W_i + jj;
        const size_t stride20 = (size_t)20 * kB * kNin;
        // two passes of 5 time-streams each (bounded register pressure)
        for (int pass = 0; pass < 2; ++pass) {
            const float* x0 = x_in + ((size_t)tslot * kB + b) * kNin +
                              (size_t)pass * 5 * stride20;
            float a0 = 0, a1 = 0, a2 = 0, a3 = 0, a4 = 0;
            for (int i = 0; i < kNin; ++i) {
                const float w = wcol[i * kNs];
                a0 = fmaf(x0[i], w, a0);
                a1 = fmaf(x0[stride20 + i], w, a1);
                a2 = fmaf(x0[2 * stride20 + i], w, a2);
                a3 = fmaf(x0[3 * stride20 + i], w, a3);
                a4 = fmaf(x0[4 * stride20 + i], w, a4);
            }
            const int tb = tslot + pass * 100;
            xi[(tb + 0) * kNs + jj] = a0;
            xi[(tb + 20) * kNs + jj] = a1;
            xi[(tb + 40) * kNs + jj] = a2;
            xi[(tb + 60) * kNs + jj] = a3;
            xi[(tb + 80) * kNs + jj] = a4;
        }
    }

    // LIF states (live only in owner lanes)
    float vs = 0, rs = 0;                         // wave 15, lane<50
    float vz0 = 0, rz0 = 0, vz1 = 0, rz1 = 0;     // wave 15
    float vh = 0, rh = 0;                         // q==0 (thread j)
    float vo0 = 0, ro0 = 0, vo1 = 0, ro1 = 0;     // wave 0
    float vy = 0, ry = 0;                         // wave 0, lane<20
    float czv = 0, facc = 0, hreg = 0;

    __syncthreads();

    for (int t = 0; t < kT; ++t) {
        // ---- S7 (wave 0): o-LIF + y-LIF epilogue of step t-1 (overlaps F) ----
        if (wave == 0 && t > 0) {
            float oa0 = 0, oa1 = 0;
#pragma unroll
            for (int g = 0; g < 8; ++g) {
                oa0 += ho_red[g][lane];
                if (lane < 36) oa1 += ho_red[g][64 + lane];
            }
            bool o0 = false, o1 = false;
            lif(vo0, ro0, oa0, o0);
            if (lane < 36) lif(vo1, ro1, oa1, o1);
            const unsigned long long om0 = __ballot(o0);
            const unsigned long long om1 = __ballot(o1);
            if (o0) idx_o[__popcll(om0 & ((1ull << lane) - 1))] = (unsigned short)lane;
            if (o1) idx_o[__popcll(om0) + __popcll(om1 & ((1ull << lane) - 1))] =
                (unsigned short)(64 + lane);
            const int co = __popcll(om0) + __popcll(om1);
            if (lane < kNout) {
                const float yx = rowsum(idx_o, co, W_o, kNout, lane);
                bool ys = false;
                lif(vy, ry, yx, ys);
                out[((size_t)(t - 1) * kB + b) * kNout + lane] = ys ? 1.0f : 0.0f;
            }
        }
        // ---- S1 (wave 15): s-LIF + z-LIF + index lists (overlaps F) ----
        if (wave == 15) {
            bool sspk = false;
            if (lane < kNs) {
                const float sx = xi[t * kNs + lane];
                lif(vs, rs, sx, sspk);
            }
            const unsigned long long sm = __ballot(sspk);
            if (sspk) idx_s[__popcll(sm & ((1ull << lane) - 1))] = (unsigned short)lane;
            const int cs = __popcll(sm);
            bool z0 = false, z1 = false;
            const float zx0 = rowsum(idx_s, cs, W_z, kNz, lane);
            lif(vz0, rz0, zx0, z0);
            if (lane < 36) {
                const float zx1 = rowsum(idx_s, cs, W_z, kNz, 64 + lane);
                lif(vz1, rz1, zx1, z1);
            }
            const unsigned long long zm0 = __ballot(z0);
            const unsigned long long zm1 = __ballot(z1);
            if (z0) idx_z[__popcll(zm0 & ((1ull << lane) - 1))] = (unsigned short)lane;
            if (z1) idx_z[__popcll(zm0) + __popcll(zm1 & ((1ull << lane) - 1))] =
                (unsigned short)(64 + lane);
            if (lane == 0) cnt_z = __popcll(zm0) + __popcll(zm1);
        }
        // ---- F (all): dense prevh @ W_h, split-K halves of 256 ----
        {
            const float* wh = W_h + j;
            const int k0 = q << 8;
            float a0 = 0.f, a1 = 0.f, a2 = 0.f, a3 = 0.f;
            for (int k = k0; k < k0 + 256; k += 8) {
                const float4 p0 = *(const float4*)&prevh[k];
                const float4 p1 = *(const float4*)&prevh[k + 4];
                a0 = fmaf(p0.x, wh[(k + 0) * kNh], a0);
                a1 = fmaf(p0.y, wh[(k + 1) * kNh], a1);
                a2 = fmaf(p0.z, wh[(k + 2) * kNh], a2);
                a3 = fmaf(p0.w, wh[(k + 3) * kNh], a3);
                a0 = fmaf(p1.x, wh[(k + 4) * kNh], a0);
                a1 = fmaf(p1.y, wh[(k + 5) * kNh], a1);
                a2 = fmaf(p1.z, wh[(k + 6) * kNh], a2);
                a3 = fmaf(p1.w, wh[(k + 7) * kNh], a3);
            }
            facc = (a0 + a1) + (a2 + a3);
            if (q) fpart[j] = facc;
        }
        __syncthreads();  // bar1

        // ---- S2 (q==0): cz rowsum + combine + h-LIF + history ballot ----
        bool hspk = false;
        if (q == 0) {
            czv = rowsum(idx_z, cnt_z, W_c, kNh, j);
            const float tot = facc + fpart[j] + czv;
            lif(vh, rh, tot, hspk);
        }
        {
            const unsigned long long hm = __ballot(hspk);
            if (q == 0 && lane == 0) hist[t][wave] = hm;
        }
        __syncthreads();  // bar2

        // ---- S3: recall coefficients ck + h index list ----
        if (tid <= t) {
            const unsigned long long* ht = hist[t];
            const unsigned long long* hk = hist[tid];
            int d = 0;
#pragma unroll
            for (int w = 0; w < 8; ++w) d += __popcll(ht[w] & hk[w]);
            ck[tid] = eta * lampow[t - tid] * (float)d;
        }
        if (q == 0) {
            const unsigned long long mw = hist[t][wave];
            if ((mw >> lane) & 1) {
                int pos = __popcll(mw & ((1ull << lane) - 1));
                for (int u = 0; u < wave; ++u) pos += __popcll(hist[t][u]);
                idx_h[pos] = (unsigned short)j;
            }
            if (tid == 0) {
                int c = 0;
#pragma unroll
                for (int u = 0; u < 8; ++u) c += __popcll(hist[t][u]);
                cnt_h = c;
            }
        }
        __syncthreads();  // bar3

        // ---- S4 (all): split sparse h@W_h rowsum + split recall loop ----
        {
            const int ch = cnt_h;
            const int ch2 = ch >> 1;
            const int half = (t + 1) >> 1;
            const int rlo = q ? ch2 : 0;
            const int rn = q ? (ch - ch2) : ch2;
            const int klo = q ? half : 0;
            const int khi = q ? (t + 1) : half;
            float part = rowsum(idx_h + rlo, rn, W_h, kNh, j);
            const int w = j >> 6, bit = j & 63;
            float racc = 0.f;
            for (int k = klo; k < khi; ++k) {
                const float c = ck[k];
                racc += ((hist[k][w] >> bit) & 1) ? c : 0.f;
            }
            part += racc;
            if (q) hpart[j] = part; else hreg = part;
        }
        __syncthreads();  // bar4

        // ---- S5 (q==0): h_new = hw + cz + recall ----
        if (q == 0) prevh[j] = hreg + hpart[j] + czv;
        __syncthreads();  // bar5

        // ---- S6: h_new @ W_ho partials (8 groups of 64 rows x 100 cols) ----
        if (tid < 800) {
            const int g = tid / kNho, j2 = tid - g * kNho;
            const float* wp = W_ho + j2;
            float s0 = 0.f, s1 = 0.f;
            const int i0 = g * 64;
            for (int i = i0; i < i0 + 64; i += 2) {
                s0 = fmaf(prevh[i], wp[i * kNho], s0);
                s1 = fmaf(prevh[i + 1], wp[(i + 1) * kNho], s1);
            }
            ho_red[g][j2] = s0 + s1;
        }
        __syncthreads();  // bar6
    }

    // ---- final epilogue for t = kT-1 ----
    if (wave == 0) {
        float oa0 = 0, oa1 = 0;
#pragma unroll
        for (int g = 0; g < 8; ++g) {
            oa0 += ho_red[g][lane];
            if (lane < 36) oa1 += ho_red[g][64 + lane];
        }
        bool o0 = false, o1 = false;
        lif(vo0, ro0, oa0, o0);
        if (lane < 36) lif(vo1, ro1, oa1, o1);
        const unsigned long long om0 = __ballot(o0);
        const unsigned long long om1 = __ballot(o1);
        if (o0) idx_o[__popcll(om0 & ((1ull << lane) - 1))] = (unsigned short)lane;
        if (o1) idx_o[__popcll(om0) + __popcll(om1 & ((1ull << lane) - 1))] =
            (unsigned short)(64 + lane);
        const int co = __popcll(om0) + __popcll(om1);
        if (lane < kNout) {
            const float yx = rowsum(idx_o, co, W_o, kNout, lane);
            bool ys = false;
            lif(vy, ry, yx, ys);
            out[((size_t)(kT - 1) * kB + b) * kNout + lane] = ys ? 1.0f : 0.0f;
        }
    }
}

extern "C" void kernel_launch(void* const* d_in, const int* in_sizes, int n_in,
                              void* d_out, int out_size, void* d_ws, size_t ws_size,
                              hipStream_t stream) {
    const float* x_in = (const float*)d_in[0];
    const float* W_i  = (const float*)d_in[1];
    const float* W_z  = (const float*)d_in[2];
    const float* W_c  = (const float*)d_in[3];
    const float* W_h  = (const float*)d_in[4];
    const float* W_ho = (const float*)d_in[5];
    const float* W_o  = (const float*)d_in[6];
    const float* lam  = (const float*)d_in[7];
    const float* eta  = (const float*)d_in[8];
    snn_seq<<<kB, 1024, 0, stream>>>(x_in, W_i, W_z, W_c, W_h, W_ho, W_o, lam, eta,
                                     (float*)d_out);
}

// Round 5
// 12939.598 us; speedup vs baseline: 1.0785x; 1.0784x over previous
//
#include <hip/hip_runtime.h>
#include <stdint.h>

namespace {
constexpr int kB = 64, kT = 200;
constexpr int kNin = 700, kNs = 50, kNz = 100, kNh = 512, kNho = 100, kNout = 20;
constexpr int kHistW = 17;   // padded history row (words); 8 used, 17 breaks bank conflicts
constexpr int kXiW = 64;     // padded xi row stride (floats)
constexpr float kDecay = 0.95f, kThresh = 0.5f, kRefrac = 2.0f;
}

// Adaptive-LIF update (REST=RESET=0, DT=1).
__device__ __forceinline__ void lif(float& v, float& r, float x, bool& spk) {
    r = fmaxf(r - 1.0f, 0.0f);
    v = kDecay * v + (r <= 0.0f ? x : 0.0f);
    spk = (v >= kThresh);
    if (spk) { v = 0.0f; r = kRefrac; }
}

// Deterministic sparse row-sum: sum_{i in lst[0..cnt)} W[i*ld + j]
__device__ __forceinline__ float rowsum(const unsigned short* lst, int cnt,
                                        const float* __restrict__ W, int ld, int j) {
    float a0 = 0.f, a1 = 0.f, a2 = 0.f, a3 = 0.f;
    int q = 0;
    for (; q + 4 <= cnt; q += 4) {
        const int i0 = lst[q], i1 = lst[q + 1], i2 = lst[q + 2], i3 = lst[q + 3];
        a0 += W[i0 * ld + j];
        a1 += W[i1 * ld + j];
        a2 += W[i2 * ld + j];
        a3 += W[i3 * ld + j];
    }
    for (; q < cnt; ++q) a0 += W[lst[q] * ld + j];
    return (a0 + a1) + (a2 + a3);
}

__global__ __launch_bounds__(1024)
__attribute__((amdgpu_waves_per_eu(4, 4)))
void snn_seq(const float* __restrict__ x_in, const float* __restrict__ W_i,
             const float* __restrict__ W_z, const float* __restrict__ W_c,
             const float* __restrict__ W_h, const float* __restrict__ W_ho,
             const float* __restrict__ W_o, const float* __restrict__ lam_p,
             const float* __restrict__ eta_p, float* __restrict__ out) {
    __shared__ unsigned long long hist[kT][kHistW];     // 27200 B: h spike history (padded)
    __shared__ float xi[kT * kXiW];                     // 51200 B: precomputed x@W_i (padded)
    __shared__ float lampow[kT];                        // 800
    __shared__ float ck[kT];                            // 800
    __shared__ __align__(16) float prevh[kNh];          // 2048: h_new state
    __shared__ float fpart[kNh];                        // 2048: dense-matvec K-half partial
    __shared__ float hpart[kNh];                        // 2048: recall/rowsum partial
    __shared__ float ho_red[8][kNho];                   // 3200: h_new@W_ho partials
    __shared__ unsigned short idx_s[kNs], idx_z[kNz], idx_h[kNh], idx_o[kNho];
    __shared__ int cnt_z, cnt_h;
    // static LDS ~90.9 KB -> exactly 1 block/CU -> RA targets 4 waves/EU (128 VGPR)

    const int tid = threadIdx.x;
    const int lane = tid & 63;
    const int wave = tid >> 6;
    const int q = tid >> 9;        // K-half / role split
    const int j = tid & 511;       // neuron index within h population
    const int b = blockIdx.x;
    const float lam = lam_p[0], eta = eta_p[0];

    // ---- prologue: lampow, prevh=0, xi = x@W_i for all t (register-tiled) ----
    if (tid == 0) {
        float p = 1.0f;
        for (int i = 0; i < kT; ++i) { lampow[i] = p; p *= lam; }
    }
    if (tid < kNh) prevh[tid] = 0.0f;
    if (tid < 1000) {
        const int jj = tid % kNs;          // output col 0..49
        const int tslot = tid / kNs;       // 0..19
        const float* wcol = W_i + jj;
        const size_t stride20 = (size_t)20 * kB * kNin;
        // two passes of 5 time-streams each (bounded register pressure)
        for (int pass = 0; pass < 2; ++pass) {
            const float* x0 = x_in + ((size_t)tslot * kB + b) * kNin +
                              (size_t)pass * 5 * stride20;
            float a0 = 0, a1 = 0, a2 = 0, a3 = 0, a4 = 0;
            for (int i = 0; i < kNin; ++i) {
                const float w = wcol[i * kNs];
                a0 = fmaf(x0[i], w, a0);
                a1 = fmaf(x0[stride20 + i], w, a1);
                a2 = fmaf(x0[2 * stride20 + i], w, a2);
                a3 = fmaf(x0[3 * stride20 + i], w, a3);
                a4 = fmaf(x0[4 * stride20 + i], w, a4);
            }
            const int tb = tslot + pass * 100;
            xi[(tb + 0) * kXiW + jj] = a0;
            xi[(tb + 20) * kXiW + jj] = a1;
            xi[(tb + 40) * kXiW + jj] = a2;
            xi[(tb + 60) * kXiW + jj] = a3;
            xi[(tb + 80) * kXiW + jj] = a4;
        }
    }

    // LIF states (live only in owner lanes)
    float vs = 0, rs = 0;                         // wave 15, lane<50
    float vz0 = 0, rz0 = 0, vz1 = 0, rz1 = 0;     // wave 15
    float vh = 0, rh = 0;                         // q==0 (thread j)
    float vo0 = 0, ro0 = 0, vo1 = 0, ro1 = 0;     // wave 0
    float vy = 0, ry = 0;                         // wave 0, lane<20
    float czv = 0, facc = 0, hreg = 0;

    __syncthreads();

    for (int t = 0; t < kT; ++t) {
        // ---- S7 (wave 0): o-LIF + y-LIF epilogue of step t-1 (overlaps F) ----
        if (wave == 0 && t > 0) {
            float oa0 = 0, oa1 = 0;
#pragma unroll
            for (int g = 0; g < 8; ++g) {
                oa0 += ho_red[g][lane];
                if (lane < 36) oa1 += ho_red[g][64 + lane];
            }
            bool o0 = false, o1 = false;
            lif(vo0, ro0, oa0, o0);
            if (lane < 36) lif(vo1, ro1, oa1, o1);
            const unsigned long long om0 = __ballot(o0);
            const unsigned long long om1 = __ballot(o1);
            if (o0) idx_o[__popcll(om0 & ((1ull << lane) - 1))] = (unsigned short)lane;
            if (o1) idx_o[__popcll(om0) + __popcll(om1 & ((1ull << lane) - 1))] =
                (unsigned short)(64 + lane);
            const int co = __popcll(om0) + __popcll(om1);
            if (lane < kNout) {
                const float yx = rowsum(idx_o, co, W_o, kNout, lane);
                bool ys = false;
                lif(vy, ry, yx, ys);
                out[((size_t)(t - 1) * kB + b) * kNout + lane] = ys ? 1.0f : 0.0f;
            }
        }
        // ---- S1 (wave 15): s-LIF + z-LIF + index lists (overlaps F) ----
        if (wave == 15) {
            bool sspk = false;
            if (lane < kNs) {
                const float sx = xi[t * kXiW + lane];
                lif(vs, rs, sx, sspk);
            }
            const unsigned long long sm = __ballot(sspk);
            if (sspk) idx_s[__popcll(sm & ((1ull << lane) - 1))] = (unsigned short)lane;
            const int cs = __popcll(sm);
            bool z0 = false, z1 = false;
            const float zx0 = rowsum(idx_s, cs, W_z, kNz, lane);
            lif(vz0, rz0, zx0, z0);
            if (lane < 36) {
                const float zx1 = rowsum(idx_s, cs, W_z, kNz, 64 + lane);
                lif(vz1, rz1, zx1, z1);
            }
            const unsigned long long zm0 = __ballot(z0);
            const unsigned long long zm1 = __ballot(z1);
            if (z0) idx_z[__popcll(zm0 & ((1ull << lane) - 1))] = (unsigned short)lane;
            if (z1) idx_z[__popcll(zm0) + __popcll(zm1 & ((1ull << lane) - 1))] =
                (unsigned short)(64 + lane);
            if (lane == 0) cnt_z = __popcll(zm0) + __popcll(zm1);
        }
        // ---- F (all): dense prevh @ W_h, split-K halves of 256 ----
        {
            const float* wh = W_h + j;
            const int k0 = q << 8;
            float a0 = 0.f, a1 = 0.f, a2 = 0.f, a3 = 0.f;
            for (int k = k0; k < k0 + 256; k += 8) {
                const float4 p0 = *(const float4*)&prevh[k];
                const float4 p1 = *(const float4*)&prevh[k + 4];
                a0 = fmaf(p0.x, wh[(k + 0) * kNh], a0);
                a1 = fmaf(p0.y, wh[(k + 1) * kNh], a1);
                a2 = fmaf(p0.z, wh[(k + 2) * kNh], a2);
                a3 = fmaf(p0.w, wh[(k + 3) * kNh], a3);
                a0 = fmaf(p1.x, wh[(k + 4) * kNh], a0);
                a1 = fmaf(p1.y, wh[(k + 5) * kNh], a1);
                a2 = fmaf(p1.z, wh[(k + 6) * kNh], a2);
                a3 = fmaf(p1.w, wh[(k + 7) * kNh], a3);
            }
            facc = (a0 + a1) + (a2 + a3);
            if (q) fpart[j] = facc;
        }
        __syncthreads();  // bar1

        // ---- S2 (q==0): cz rowsum + combine + h-LIF + history ballot ----
        bool hspk = false;
        if (q == 0) {
            czv = rowsum(idx_z, cnt_z, W_c, kNh, j);
            const float tot = facc + fpart[j] + czv;
            lif(vh, rh, tot, hspk);
        }
        {
            const unsigned long long hm = __ballot(hspk);
            if (q == 0 && lane == 0) hist[t][wave] = hm;
        }
        __syncthreads();  // bar2

        // ---- S3: recall coefficients ck + h index list ----
        if (tid <= t) {
            const unsigned long long* ht = hist[t];
            const unsigned long long* hk = hist[tid];
            int d = 0;
#pragma unroll
            for (int w = 0; w < 8; ++w) d += __popcll(ht[w] & hk[w]);
            ck[tid] = eta * lampow[t - tid] * (float)d;
        }
        if (q == 0) {
            const unsigned long long mw = hist[t][wave];
            if ((mw >> lane) & 1) {
                int pos = __popcll(mw & ((1ull << lane) - 1));
                for (int u = 0; u < wave; ++u) pos += __popcll(hist[t][u]);
                idx_h[pos] = (unsigned short)j;
            }
            if (tid == 0) {
                int c = 0;
#pragma unroll
                for (int u = 0; u < 8; ++u) c += __popcll(hist[t][u]);
                cnt_h = c;
            }
        }
        __syncthreads();  // bar3

        // ---- S4 (all): split sparse h@W_h rowsum + split recall loop ----
        {
            const int ch = cnt_h;
            const int ch2 = ch >> 1;
            const int half = (t + 1) >> 1;
            const int rlo = q ? ch2 : 0;
            const int rn = q ? (ch - ch2) : ch2;
            const int klo = q ? half : 0;
            const int khi = q ? (t + 1) : half;
            float part = rowsum(idx_h + rlo, rn, W_h, kNh, j);
            const int w = j >> 6, bit = j & 63;
            float racc = 0.f;
            for (int k = klo; k < khi; ++k) {
                const float c = ck[k];
                racc += ((hist[k][w] >> bit) & 1) ? c : 0.f;
            }
            part += racc;
            if (q) hpart[j] = part; else hreg = part;
        }
        __syncthreads();  // bar4

        // ---- S5 (q==0): h_new = hw + cz + recall ----
        if (q == 0) prevh[j] = hreg + hpart[j] + czv;
        __syncthreads();  // bar5

        // ---- S6: h_new @ W_ho partials (8 groups of 64 rows x 100 cols) ----
        if (tid < 800) {
            const int g = tid / kNho, j2 = tid - g * kNho;
            const float* wp = W_ho + j2;
            float s0 = 0.f, s1 = 0.f;
            const int i0 = g * 64;
            for (int i = i0; i < i0 + 64; i += 2) {
                s0 = fmaf(prevh[i], wp[i * kNho], s0);
                s1 = fmaf(prevh[i + 1], wp[(i + 1) * kNho], s1);
            }
            ho_red[g][j2] = s0 + s1;
        }
        __syncthreads();  // bar6
    }

    // ---- final epilogue for t = kT-1 ----
    if (wave == 0) {
        float oa0 = 0, oa1 = 0;
#pragma unroll
        for (int g = 0; g < 8; ++g) {
            oa0 += ho_red[g][lane];
            if (lane < 36) oa1 += ho_red[g][64 + lane];
        }
        bool o0 = false, o1 = false;
        lif(vo0, ro0, oa0, o0);
        if (lane < 36) lif(vo1, ro1, oa1, o1);
        const unsigned long long om0 = __ballot(o0);
        const unsigned long long om1 = __ballot(o1);
        if (o0) idx_o[__popcll(om0 & ((1ull << lane) - 1))] = (unsigned short)lane;
        if (o1) idx_o[__popcll(om0) + __popcll(om1 & ((1ull << lane) - 1))] =
            (unsigned short)(64 + lane);
        const int co = __popcll(om0) + __popcll(om1);
        if (lane < kNout) {
            const float yx = rowsum(idx_o, co, W_o, kNout, lane);
            bool ys = false;
            lif(vy, ry, yx, ys);
            out[((size_t)(kT - 1) * kB + b) * kNout + lane] = ys ? 1.0f : 0.0f;
        }
    }
}

extern "C" void kernel_launch(void* const* d_in, const int* in_sizes, int n_in,
                              void* d_out, int out_size, void* d_ws, size_t ws_size,
                              hipStream_t stream) {
    const float* x_in = (const float*)d_in[0];
    const float* W_i  = (const float*)d_in[1];
    const float* W_z  = (const float*)d_in[2];
    const float* W_c  = (const float*)d_in[3];
    const float* W_h  = (const float*)d_in[4];
    const float* W_ho = (const float*)d_in[5];
    const float* W_o  = (const float*)d_in[6];
    const float* lam  = (const float*)d_in[7];
    const float* eta  = (const float*)d_in[8];
    snn_seq<<<kB, 1024, 0, stream>>>(x_in, W_i, W_z, W_c, W_h, W_ho, W_o, lam, eta,
                                     (float*)d_out);
}

// Round 6
// 10254.150 us; speedup vs baseline: 1.3610x; 1.2619x over previous
//
#include <hip/hip_runtime.h>
#include <stdint.h>

namespace {
constexpr int kB = 64, kT = 200;
constexpr int kNin = 700, kNs = 50, kNz = 100, kNh = 512, kNho = 100, kNout = 20;
constexpr int kHistW = 17;   // padded history row (words); 8 used; breaks S3 bank conflicts
constexpr float kDecay = 0.95f, kThresh = 0.5f, kRefrac = 2.0f;
}

// Adaptive-LIF update (REST=RESET=0, DT=1).
__device__ __forceinline__ void lif(float& v, float& r, float x, bool& spk) {
    r = fmaxf(r - 1.0f, 0.0f);
    v = kDecay * v + (r <= 0.0f ? x : 0.0f);
    spk = (v >= kThresh);
    if (spk) { v = 0.0f; r = kRefrac; }
}

// Deterministic sparse row-sum: sum_{i in lst[0..cnt)} W[i*ld + j]
__device__ __forceinline__ float rowsum(const unsigned short* lst, int cnt,
                                        const float* __restrict__ W, int ld, int j) {
    float a0 = 0.f, a1 = 0.f, a2 = 0.f, a3 = 0.f;
    int q = 0;
    for (; q + 4 <= cnt; q += 4) {
        const int i0 = lst[q], i1 = lst[q + 1], i2 = lst[q + 2], i3 = lst[q + 3];
        a0 += W[i0 * ld + j];
        a1 += W[i1 * ld + j];
        a2 += W[i2 * ld + j];
        a3 += W[i3 * ld + j];
    }
    for (; q < cnt; ++q) a0 += W[lst[q] * ld + j];
    return (a0 + a1) + (a2 + a3);
}

__global__ __launch_bounds__(1024)
void snn_seq(const float* __restrict__ x_in, const float* __restrict__ W_i,
             const float* __restrict__ W_z, const float* __restrict__ W_c,
             const float* __restrict__ W_h, const float* __restrict__ W_ho,
             const float* __restrict__ W_o, const float* __restrict__ lam_p,
             const float* __restrict__ eta_p, float* __restrict__ out) {
    __shared__ unsigned long long hist[kT][kHistW];     // 27200 B
    __shared__ float xi[kT * kNs];                      // 40000 B
    __shared__ float lampow[kT];                        // 800
    __shared__ float ck[kT];                            // 800
    __shared__ __align__(16) float prevh[kNh];          // 2048
    __shared__ float fpart[kNh];                        // 2048
    __shared__ float hpart[kNh];                        // 2048
    __shared__ float czbuf[kNh];                        // 2048
    __shared__ float ho_red[10][kNho];                  // 4000
    __shared__ unsigned short idx_s[kNs], idx_z[kNz], idx_h[kNh], idx_o[kNho];
    __shared__ int cnt_z, cnt_h;

    const int tid = threadIdx.x;
    const int lane = tid & 63;
    const int wave = tid >> 6;     // 0..15
    const int q = tid >> 9;        // K-half / role split
    const int j = tid & 511;       // h-neuron index
    const int b = blockIdx.x;
    const float lam = lam_p[0], eta = eta_p[0];

    // ---- prologue ----
    if (tid == 0) {
        float p = 1.0f;
        for (int i = 0; i < kT; ++i) { lampow[i] = p; p *= lam; }
    }
    if (tid < kNh) prevh[tid] = 0.0f;
    if (tid < 1000) {
        const int jj = tid % kNs;          // col 0..49
        const int tslot = tid / kNs;       // 0..19
        const float* wcol = W_i + jj;
        const size_t str20 = (size_t)20 * kB * kNin;
        for (int p = 0; p < 5; ++p) {      // 5 passes x 2 time-streams (low pressure)
            const int tb = tslot + 40 * p;
            const float* x0 = x_in + ((size_t)tb * kB + b) * kNin;
            float a0 = 0.f, a1 = 0.f;
            for (int i = 0; i < kNin; ++i) {
                const float w = wcol[i * kNs];
                a0 = fmaf(x0[i], w, a0);
                a1 = fmaf(x0[str20 + i], w, a1);
            }
            xi[tb * kNs + jj] = a0;
            xi[(tb + 20) * kNs + jj] = a1;
        }
    }

    // LIF states (owner lanes only; disjoint waves)
    float vs = 0, rs = 0, vz0 = 0, rz0 = 0, vz1 = 0, rz1 = 0;   // wave 0
    float vh = 0, rh = 0, czv = 0, facc = 0, hreg = 0;          // q==0
    float vo0 = 0, ro0 = 0, vo1 = 0, ro1 = 0, vy = 0, ry = 0;   // wave 8

    __syncthreads();

    for (int t = 0; t < kT; ++t) {
        // ---- P0: wave0 = s/z stage; wave8 = o/y epilogue of t-1 ----
        if (wave == 0) {
            bool sspk = false;
            if (lane < kNs) lif(vs, rs, xi[t * kNs + lane], sspk);
            const unsigned long long sm = __ballot(sspk);
            if (sspk) idx_s[__popcll(sm & ((1ull << lane) - 1))] = (unsigned short)lane;
            const int cs = __popcll(sm);
            bool z0 = false, z1 = false;
            if (lane < kNs) {
                lif(vz0, rz0, rowsum(idx_s, cs, W_z, kNz, lane), z0);
                lif(vz1, rz1, rowsum(idx_s, cs, W_z, kNz, lane + 50), z1);
            }
            const unsigned long long zm0 = __ballot(z0);
            const unsigned long long zm1 = __ballot(z1);
            if (z0) idx_z[__popcll(zm0 & ((1ull << lane) - 1))] = (unsigned short)lane;
            if (z1) idx_z[__popcll(zm0) + __popcll(zm1 & ((1ull << lane) - 1))] =
                (unsigned short)(lane + 50);
            if (lane == 0) cnt_z = __popcll(zm0) + __popcll(zm1);
        } else if (wave == 8 && t > 0) {
            bool o0 = false, o1 = false;
            if (lane < kNs) {
                float s0 = 0.f, s1 = 0.f;
#pragma unroll
                for (int g = 0; g < 10; ++g) {
                    s0 += ho_red[g][lane];
                    s1 += ho_red[g][lane + 50];
                }
                lif(vo0, ro0, s0, o0);
                lif(vo1, ro1, s1, o1);
            }
            const unsigned long long om0 = __ballot(o0);
            const unsigned long long om1 = __ballot(o1);
            if (o0) idx_o[__popcll(om0 & ((1ull << lane) - 1))] = (unsigned short)lane;
            if (o1) idx_o[__popcll(om0) + __popcll(om1 & ((1ull << lane) - 1))] =
                (unsigned short)(lane + 50);
            const int co = __popcll(om0) + __popcll(om1);
            if (lane < kNout) {
                bool ys = false;
                lif(vy, ry, rowsum(idx_o, co, W_o, kNout, lane), ys);
                out[((size_t)(t - 1) * kB + b) * kNout + lane] = ys ? 1.0f : 0.0f;
            }
        }
        __syncthreads();  // bar1

        // ---- F: dense prevh @ W_h split-K; q1 also computes cz into czbuf ----
        {
            const float* wh = W_h + j;
            const int k0 = q << 8;
            float a0 = 0.f, a1 = 0.f, a2 = 0.f, a3 = 0.f;
            for (int k = k0; k < k0 + 256; k += 8) {
                const float4 p0 = *(const float4*)&prevh[k];
                const float4 p1 = *(const float4*)&prevh[k + 4];
                a0 = fmaf(p0.x, wh[(k + 0) * kNh], a0);
                a1 = fmaf(p0.y, wh[(k + 1) * kNh], a1);
                a2 = fmaf(p0.z, wh[(k + 2) * kNh], a2);
                a3 = fmaf(p0.w, wh[(k + 3) * kNh], a3);
                a0 = fmaf(p1.x, wh[(k + 4) * kNh], a0);
                a1 = fmaf(p1.y, wh[(k + 5) * kNh], a1);
                a2 = fmaf(p1.z, wh[(k + 6) * kNh], a2);
                a3 = fmaf(p1.w, wh[(k + 7) * kNh], a3);
            }
            facc = (a0 + a1) + (a2 + a3);
            if (q) {
                fpart[j] = facc;
                czbuf[j] = rowsum(idx_z, cnt_z, W_c, kNh, j);
            }
        }
        __syncthreads();  // bar2

        // ---- S2 (q0): h-LIF + history ballot ----
        bool hspk = false;
        if (q == 0) {
            czv = czbuf[j];
            lif(vh, rh, facc + fpart[j] + czv, hspk);
        }
        if (wave < 8) {
            const unsigned long long hm = __ballot(hspk);
            if (lane == 0) hist[t][wave] = hm;
        }
        __syncthreads();  // bar3

        // ---- S3: ck (q1 threads) + idx_h build (q0) ----
        {
            const int k = tid - 512;
            if (q == 1 && k <= t) {
                int d = 0;
#pragma unroll
                for (int w = 0; w < 8; ++w) d += __popcll(hist[t][w] & hist[k][w]);
                ck[k] = eta * lampow[t - k] * (float)d;
            }
            if (q == 0) {
                const unsigned long long mw = hist[t][wave];
                if ((mw >> lane) & 1) {
                    int pos = __popcll(mw & ((1ull << lane) - 1));
                    for (int u = 0; u < wave; ++u) pos += __popcll(hist[t][u]);
                    idx_h[pos] = (unsigned short)j;
                }
                if (tid == 0) {
                    int c = 0;
#pragma unroll
                    for (int u = 0; u < 8; ++u) c += __popcll(hist[t][u]);
                    cnt_h = c;
                }
            }
        }
        __syncthreads();  // bar4

        // ---- S4: split sparse h@W_h + split recall ----
        {
            const int ch = cnt_h, ch2 = ch >> 1;
            const int half = (t + 1) >> 1;
            const int rlo = q ? ch2 : 0;
            const int rn = q ? (ch - ch2) : ch2;
            const int klo = q ? half : 0;
            const int khi = q ? (t + 1) : half;
            float part = rowsum(idx_h + rlo, rn, W_h, kNh, j);
            const int w = j >> 6, bit = j & 63;
            float racc = 0.f;
            for (int k = klo; k < khi; ++k)
                racc += ((hist[k][w] >> bit) & 1) ? ck[k] : 0.f;
            part += racc;
            if (q) hpart[j] = part; else hreg = part;
        }
        __syncthreads();  // bar5

        // ---- S5 (q0): finalize h_new ----
        if (q == 0) prevh[j] = hreg + hpart[j] + czv;
        __syncthreads();  // bar6

        // ---- S6: h_new @ W_ho partials (10 groups of 51/52 rows x 100 cols) ----
        if (tid < 1000) {
            const int g = tid / kNho, c = tid - g * kNho;
            const int i0 = g * 51 + (g >= 9 ? 1 : 0);
            const int icnt = 51 + (g >= 8 ? 1 : 0);
            const float* wp = W_ho + c;
            float s0 = 0.f, s1 = 0.f;
            int i = i0;
            for (; i + 2 <= i0 + icnt; i += 2) {
                s0 = fmaf(prevh[i], wp[i * kNho], s0);
                s1 = fmaf(prevh[i + 1], wp[(i + 1) * kNho], s1);
            }
            if (i < i0 + icnt) s0 = fmaf(prevh[i], wp[i * kNho], s0);
            ho_red[g][c] = s0 + s1;
        }
        __syncthreads();  // bar7
    }

    // ---- final o/y epilogue (t = kT-1), wave 8 ----
    if (wave == 8) {
        bool o0 = false, o1 = false;
        if (lane < kNs) {
            float s0 = 0.f, s1 = 0.f;
#pragma unroll
            for (int g = 0; g < 10; ++g) {
                s0 += ho_red[g][lane];
                s1 += ho_red[g][lane + 50];
            }
            lif(vo0, ro0, s0, o0);
            lif(vo1, ro1, s1, o1);
        }
        const unsigned long long om0 = __ballot(o0);
        const unsigned long long om1 = __ballot(o1);
        if (o0) idx_o[__popcll(om0 & ((1ull << lane) - 1))] = (unsigned short)lane;
        if (o1) idx_o[__popcll(om0) + __popcll(om1 & ((1ull << lane) - 1))] =
            (unsigned short)(lane + 50);
        const int co = __popcll(om0) + __popcll(om1);
        if (lane < kNout) {
            bool ys = false;
            lif(vy, ry, rowsum(idx_o, co, W_o, kNout, lane), ys);
            out[((size_t)(kT - 1) * kB + b) * kNout + lane] = ys ? 1.0f : 0.0f;
        }
    }
}

extern "C" void kernel_launch(void* const* d_in, const int* in_sizes, int n_in,
                              void* d_out, int out_size, void* d_ws, size_t ws_size,
                              hipStream_t stream) {
    const float* x_in = (const float*)d_in[0];
    const float* W_i  = (const float*)d_in[1];
    const float* W_z  = (const float*)d_in[2];
    const float* W_c  = (const float*)d_in[3];
    const float* W_h  = (const float*)d_in[4];
    const float* W_ho = (const float*)d_in[5];
    const float* W_o  = (const float*)d_in[6];
    const float* lam  = (const float*)d_in[7];
    const float* eta  = (const float*)d_in[8];
    snn_seq<<<kB, 1024, 0, stream>>>(x_in, W_i, W_z, W_c, W_h, W_ho, W_o, lam, eta,
                                     (float*)d_out);
}

// Round 7
// 5650.969 us; speedup vs baseline: 2.4696x; 1.8146x over previous
//
#include <hip/hip_runtime.h>
#include <stdint.h>

namespace {
constexpr int kB = 64, kT = 200;
constexpr int kNin = 700, kNs = 50, kNz = 100, kNh = 512, kNho = 100, kNout = 20;
constexpr int kHistW = 17;   // padded history row (words); 8 used
constexpr int kXiW = 64;     // padded xi row stride (floats)
constexpr float kDecay = 0.95f, kThresh = 0.5f, kRefrac = 2.0f;
}

// Adaptive-LIF update (REST=RESET=0, DT=1).
__device__ __forceinline__ void lif(float& v, float& r, float x, bool& spk) {
    r = fmaxf(r - 1.0f, 0.0f);
    v = kDecay * v + (r <= 0.0f ? x : 0.0f);
    spk = (v >= kThresh);
    if (spk) { v = 0.0f; r = kRefrac; }
}

// Deterministic sparse row-sum: sum_{i in lst[0..cnt)} W[i*ld + j]
__device__ __forceinline__ float rowsum(const unsigned short* lst, int cnt,
                                        const float* __restrict__ W, int ld, int j) {
    float a0 = 0.f, a1 = 0.f, a2 = 0.f, a3 = 0.f;
    int q = 0;
    for (; q + 4 <= cnt; q += 4) {
        const int i0 = lst[q], i1 = lst[q + 1], i2 = lst[q + 2], i3 = lst[q + 3];
        a0 += W[i0 * ld + j];
        a1 += W[i1 * ld + j];
        a2 += W[i2 * ld + j];
        a3 += W[i3 * ld + j];
    }
    for (; q < cnt; ++q) a0 += W[lst[q] * ld + j];
    return (a0 + a1) + (a2 + a3);
}

__global__ __launch_bounds__(512, 1)
void snn_seq(const float* __restrict__ x_in, const float* __restrict__ W_i,
             const float* __restrict__ W_z, const float* __restrict__ W_c,
             const float* __restrict__ W_h, const float* __restrict__ W_ho,
             const float* __restrict__ W_o, const float* __restrict__ lam_p,
             const float* __restrict__ eta_p, float* __restrict__ out) {
    __shared__ unsigned long long hist[kT][kHistW];     // 27200 B
    __shared__ float xi[kT * kXiW];                     // 51200 B
    __shared__ float lampow[kT];                        // 800
    __shared__ float ck[kT];                            // 800
    __shared__ __align__(16) float prevh[kNh];          // 2048
    __shared__ float ho_red[5][kNho];                   // 2000
    __shared__ unsigned short idx_s[kNs], idx_z[kNz], idx_h[kNh], idx_o[kNho];
    __shared__ int cnt_z, cnt_h;
    // static LDS ~83.6 KB: 1 block/CU -> 2 waves/EU -> generous VGPR budget

    const int tid = threadIdx.x;
    const int lane = tid & 63;
    const int wave = tid >> 6;     // 0..7
    const int j = tid;             // h-neuron index (0..511)
    const int b = blockIdx.x;
    const float lam = lam_p[0], eta = eta_p[0];

    // ---- prologue: lampow, prevh=0, xi = x@W_i for all t ----
    if (tid == 0) {
        float p = 1.0f;
        for (int i = 0; i < kT; ++i) { lampow[i] = p; p *= lam; }
    }
    prevh[tid] = 0.0f;
    if (tid < 500) {
        const int jj = tid % kNs;          // col 0..49
        const int tslot = tid / kNs;       // 0..9
        const float* wcol = W_i + jj;
        const size_t str10 = (size_t)10 * kB * kNin;
        for (int p = 0; p < 5; ++p) {      // 5 passes x 4 time-streams
            const int tb = tslot + 40 * p;
            const float* x0 = x_in + ((size_t)tb * kB + b) * kNin;
            float a0 = 0.f, a1 = 0.f, a2 = 0.f, a3 = 0.f;
            for (int i = 0; i < kNin; ++i) {
                const float w = wcol[i * kNs];
                a0 = fmaf(x0[i], w, a0);
                a1 = fmaf(x0[str10 + i], w, a1);
                a2 = fmaf(x0[2 * str10 + i], w, a2);
                a3 = fmaf(x0[3 * str10 + i], w, a3);
            }
            xi[(tb + 0) * kXiW + jj] = a0;
            xi[(tb + 10) * kXiW + jj] = a1;
            xi[(tb + 20) * kXiW + jj] = a2;
            xi[(tb + 30) * kXiW + jj] = a3;
        }
    }

    // LIF states (owner lanes only; disjoint waves)
    float vs = 0, rs = 0, vz0 = 0, rz0 = 0, vz1 = 0, rz1 = 0;   // wave 0, lane<50
    float vo0 = 0, ro0 = 0, vo1 = 0, ro1 = 0, vy = 0, ry = 0;   // wave 4
    float vh = 0, rh = 0, czv = 0;                              // all threads

    __syncthreads();

    for (int t = 0; t < kT; ++t) {
        // ---- P0: wave0 = s/z stage; wave4 = o/y epilogue of t-1 ----
        if (wave == 0) {
            bool sspk = false;
            if (lane < kNs) lif(vs, rs, xi[t * kXiW + lane], sspk);
            const unsigned long long sm = __ballot(sspk);
            if (sspk) idx_s[__popcll(sm & ((1ull << lane) - 1))] = (unsigned short)lane;
            const int cs = __popcll(sm);
            bool z0 = false, z1 = false;
            if (lane < kNs) {
                lif(vz0, rz0, rowsum(idx_s, cs, W_z, kNz, lane), z0);
                lif(vz1, rz1, rowsum(idx_s, cs, W_z, kNz, lane + 50), z1);
            }
            const unsigned long long zm0 = __ballot(z0);
            const unsigned long long zm1 = __ballot(z1);
            if (z0) idx_z[__popcll(zm0 & ((1ull << lane) - 1))] = (unsigned short)lane;
            if (z1) idx_z[__popcll(zm0) + __popcll(zm1 & ((1ull << lane) - 1))] =
                (unsigned short)(lane + 50);
            if (lane == 0) cnt_z = __popcll(zm0) + __popcll(zm1);
        } else if (wave == 4 && t > 0) {
            bool o0 = false, o1 = false;
            if (lane < kNs) {
                float s0 = 0.f, s1 = 0.f;
#pragma unroll
                for (int g = 0; g < 5; ++g) {
                    s0 += ho_red[g][lane];
                    s1 += ho_red[g][lane + 50];
                }
                lif(vo0, ro0, s0, o0);
                lif(vo1, ro1, s1, o1);
            }
            const unsigned long long om0 = __ballot(o0);
            const unsigned long long om1 = __ballot(o1);
            if (o0) idx_o[__popcll(om0 & ((1ull << lane) - 1))] = (unsigned short)lane;
            if (o1) idx_o[__popcll(om0) + __popcll(om1 & ((1ull << lane) - 1))] =
                (unsigned short)(lane + 50);
            const int co = __popcll(om0) + __popcll(om1);
            if (lane < kNout) {
                bool ys = false;
                lif(vy, ry, rowsum(idx_o, co, W_o, kNout, lane), ys);
                out[((size_t)(t - 1) * kB + b) * kNout + lane] = ys ? 1.0f : 0.0f;
            }
        }
        __syncthreads();  // bar1

        // ---- F: dense prevh @ W_h (full K per thread, 32-deep load batches)
        //      + cz rowsum + h-LIF + history ballot ----
        {
            const float* wh = W_h + j;
            float a0 = 0.f, a1 = 0.f, a2 = 0.f, a3 = 0.f;
            for (int k = 0; k < kNh; k += 32) {
                float w[32];
#pragma unroll
                for (int u = 0; u < 32; ++u) w[u] = wh[(size_t)(k + u) * kNh];
#pragma unroll
                for (int u = 0; u < 32; u += 4) {
                    const float4 p = *(const float4*)&prevh[k + u];
                    a0 = fmaf(p.x, w[u + 0], a0);
                    a1 = fmaf(p.y, w[u + 1], a1);
                    a2 = fmaf(p.z, w[u + 2], a2);
                    a3 = fmaf(p.w, w[u + 3], a3);
                }
            }
            czv = rowsum(idx_z, cnt_z, W_c, kNh, j);
            bool hspk = false;
            lif(vh, rh, ((a0 + a1) + (a2 + a3)) + czv, hspk);
            const unsigned long long hm = __ballot(hspk);
            if (lane == 0) hist[t][wave] = hm;
        }
        __syncthreads();  // bar2

        // ---- S3: ck coefficients + idx_h build ----
        if (tid <= t) {
            int d = 0;
#pragma unroll
            for (int w = 0; w < 8; ++w) d += __popcll(hist[t][w] & hist[tid][w]);
            ck[tid] = eta * lampow[t - tid] * (float)d;
        }
        {
            const unsigned long long mw = hist[t][wave];
            if ((mw >> lane) & 1) {
                int pos = __popcll(mw & ((1ull << lane) - 1));
                for (int u = 0; u < wave; ++u) pos += __popcll(hist[t][u]);
                idx_h[pos] = (unsigned short)j;
            }
            if (tid == 0) {
                int c = 0;
#pragma unroll
                for (int u = 0; u < 8; ++u) c += __popcll(hist[t][u]);
                cnt_h = c;
            }
        }
        __syncthreads();  // bar3

        // ---- S4: sparse h@W_h + recall; finalize h_new ----
        {
            const float part = rowsum(idx_h, cnt_h, W_h, kNh, j);
            const int w = j >> 6, bit = j & 63;
            float racc = 0.f;
            for (int k = 0; k <= t; ++k)
                racc += ((hist[k][w] >> bit) & 1) ? ck[k] : 0.f;
            prevh[j] = (part + racc) + czv;
        }
        __syncthreads();  // bar4

        // ---- S6: h_new @ W_ho partials (5 groups x 100 cols) ----
        if (tid < 500) {
            const int g = tid / kNho, c = tid - g * kNho;
            const int i0 = g * 102 + (g < 2 ? g : 2);
            const int icnt = 102 + (g < 2 ? 1 : 0);
            const float* wp = W_ho + c;
            float s0 = 0.f, s1 = 0.f;
            int i = i0;
            for (; i + 2 <= i0 + icnt; i += 2) {
                s0 = fmaf(prevh[i], wp[i * kNho], s0);
                s1 = fmaf(prevh[i + 1], wp[(i + 1) * kNho], s1);
            }
            if (i < i0 + icnt) s0 = fmaf(prevh[i], wp[i * kNho], s0);
            ho_red[g][c] = s0 + s1;
        }
        __syncthreads();  // bar5
    }

    // ---- final o/y epilogue (t = kT-1), wave 4 ----
    if (wave == 4) {
        bool o0 = false, o1 = false;
        if (lane < kNs) {
            float s0 = 0.f, s1 = 0.f;
#pragma unroll
            for (int g = 0; g < 5; ++g) {
                s0 += ho_red[g][lane];
                s1 += ho_red[g][lane + 50];
            }
            lif(vo0, ro0, s0, o0);
            lif(vo1, ro1, s1, o1);
        }
        const unsigned long long om0 = __ballot(o0);
        const unsigned long long om1 = __ballot(o1);
        if (o0) idx_o[__popcll(om0 & ((1ull << lane) - 1))] = (unsigned short)lane;
        if (o1) idx_o[__popcll(om0) + __popcll(om1 & ((1ull << lane) - 1))] =
            (unsigned short)(lane + 50);
        const int co = __popcll(om0) + __popcll(om1);
        if (lane < kNout) {
            bool ys = false;
            lif(vy, ry, rowsum(idx_o, co, W_o, kNout, lane), ys);
            out[((size_t)(kT - 1) * kB + b) * kNout + lane] = ys ? 1.0f : 0.0f;
        }
    }
}

extern "C" void kernel_launch(void* const* d_in, const int* in_sizes, int n_in,
                              void* d_out, int out_size, void* d_ws, size_t ws_size,
                              hipStream_t stream) {
    const float* x_in = (const float*)d_in[0];
    const float* W_i  = (const float*)d_in[1];
    const float* W_z  = (const float*)d_in[2];
    const float* W_c  = (const float*)d_in[3];
    const float* W_h  = (const float*)d_in[4];
    const float* W_ho = (const float*)d_in[5];
    const float* W_o  = (const float*)d_in[6];
    const float* lam  = (const float*)d_in[7];
    const float* eta  = (const float*)d_in[8];
    snn_seq<<<kB, 512, 0, stream>>>(x_in, W_i, W_z, W_c, W_h, W_ho, W_o, lam, eta,
                                    (float*)d_out);
}

// Round 8
// 5453.622 us; speedup vs baseline: 2.5590x; 1.0362x over previous
//
#include <hip/hip_runtime.h>
#include <stdint.h>

namespace {
constexpr int kB = 64, kT = 200;
constexpr int kNin = 700, kNs = 50, kNz = 100, kNh = 512, kNho = 100, kNout = 20;
constexpr int kQN = 4;                 // blocks per sample (h-dim split)
constexpr int kCols = kNh / kQN;       // 128 h-columns per block
constexpr int kHistW = 17;             // padded history row (u64); 8 used
constexpr int kXiW = 64;               // padded xi row stride (floats)
constexpr float kDecay = 0.95f, kThresh = 0.5f, kRefrac = 2.0f;
constexpr unsigned kTag = 0x5A5B0000u; // epoch tag (collision-proof vs 0/0xAA..)
}

#define AGENT __HIP_MEMORY_SCOPE_AGENT

// Adaptive-LIF update (REST=RESET=0, DT=1).
__device__ __forceinline__ void lif(float& v, float& r, float x, bool& spk) {
    r = fmaxf(r - 1.0f, 0.0f);
    v = kDecay * v + (r <= 0.0f ? x : 0.0f);
    spk = (v >= kThresh);
    if (spk) { v = 0.0f; r = kRefrac; }
}

// Deterministic sparse row-sum: sum_{i in lst[0..cnt)} W[i*ld + j]
__device__ __forceinline__ float rowsum(const unsigned short* lst, int cnt,
                                        const float* __restrict__ W, int ld, int j) {
    float a0 = 0.f, a1 = 0.f, a2 = 0.f, a3 = 0.f;
    int q = 0;
    for (; q + 4 <= cnt; q += 4) {
        const int i0 = lst[q], i1 = lst[q + 1], i2 = lst[q + 2], i3 = lst[q + 3];
        a0 += W[i0 * ld + j];
        a1 += W[i1 * ld + j];
        a2 += W[i2 * ld + j];
        a3 += W[i3 * ld + j];
    }
    for (; q < cnt; ++q) a0 += W[lst[q] * ld + j];
    return (a0 + a1) + (a2 + a3);
}

__global__ __launch_bounds__(512, 1)
void snn_seq(const float* __restrict__ x_in, const float* __restrict__ W_i,
             const float* __restrict__ W_z, const float* __restrict__ W_c,
             const float* __restrict__ W_h, const float* __restrict__ W_ho,
             const float* __restrict__ W_o, const float* __restrict__ lam_p,
             const float* __restrict__ eta_p, float* __restrict__ out,
             unsigned* __restrict__ flags, unsigned long long* __restrict__ masks,
             float* __restrict__ hnew, float* __restrict__ hop) {
    __shared__ unsigned long long hist[kT][kHistW];     // 27200 B (full 512-bit hist)
    __shared__ float xi[kT * kXiW];                     // 51200 B
    __shared__ float lampow[kT];                        // 800
    __shared__ float ck[kT];                            // 800
    __shared__ __align__(16) float prevh[kNh];          // 2048 (full h_new)
    __shared__ float fpart[kQN][kCols];                 // 2048
    __shared__ float spart[kQN][kCols];                 // 2048
    __shared__ float hored[5][kNho];                    // 2000
    __shared__ unsigned short idx_s[kNs], idx_z[kNz], idx_h[kNh], idx_o[kNho];
    __shared__ int cnt_z, cnt_h;

    const int tid = threadIdx.x;
    const int lane = tid & 63;
    const int wave = tid >> 6;            // 0..7
    const int s = blockIdx.x & 63;        // sample
    const int q = blockIdx.x >> 6;        // h-slice 0..3 (group {s,s+64,s+128,s+192})
    const int cl = tid & (kCols - 1);     // column within slice
    const int kq = tid >> 7;              // K-quarter / row-quarter
    const int colg = q * kCols + cl;      // global h column
    const int g4 = (s * kQN + q) * 4;     // my flag base
    const int b = s;
    const float lam = lam_p[0], eta = eta_p[0];

    // ---- prologue: lampow, prevh=0, xi = x@W_i for all t (replicated per block) ----
    if (tid == 0) {
        float p = 1.0f;
        for (int i = 0; i < kT; ++i) { lampow[i] = p; p *= lam; }
    }
    prevh[tid] = 0.0f;
    if (tid < 500) {
        const int jj = tid % kNs;
        const int tslot = tid / kNs;      // 0..9
        const float* wcol = W_i + jj;
        const size_t str10 = (size_t)10 * kB * kNin;
        for (int p = 0; p < 5; ++p) {
            const int tb = tslot + 40 * p;
            const float* x0 = x_in + ((size_t)tb * kB + b) * kNin;
            float a0 = 0.f, a1 = 0.f, a2 = 0.f, a3 = 0.f;
            for (int i = 0; i < kNin; ++i) {
                const float w = wcol[i * kNs];
                a0 = fmaf(x0[i], w, a0);
                a1 = fmaf(x0[str10 + i], w, a1);
                a2 = fmaf(x0[2 * str10 + i], w, a2);
                a3 = fmaf(x0[3 * str10 + i], w, a3);
            }
            xi[(tb + 0) * kXiW + jj] = a0;
            xi[(tb + 10) * kXiW + jj] = a1;
            xi[(tb + 20) * kXiW + jj] = a2;
            xi[(tb + 30) * kXiW + jj] = a3;
        }
    }

    // LIF states (owner lanes only)
    float vs = 0, rs = 0, vz0 = 0, rz0 = 0, vz1 = 0, rz1 = 0;   // wave 0, replicated
    float vo0 = 0, ro0 = 0, vo1 = 0, ro1 = 0, vy = 0, ry = 0;   // q0, wave 4
    float vh = 0, rh = 0, czv = 0;                              // tid<128 (own slice)

    __syncthreads();

    for (int t = 0; t < kT; ++t) {
        // ---- P0: wave0 = s/z (replicated); q0-wave4 = o/y epilogue of t-1 ----
        if (wave == 0) {
            bool sspk = false;
            if (lane < kNs) lif(vs, rs, xi[t * kXiW + lane], sspk);
            const unsigned long long sm = __ballot(sspk);
            if (sspk) idx_s[__popcll(sm & ((1ull << lane) - 1))] = (unsigned short)lane;
            const int cs = __popcll(sm);
            bool z0 = false, z1 = false;
            if (lane < kNs) {
                lif(vz0, rz0, rowsum(idx_s, cs, W_z, kNz, lane), z0);
                lif(vz1, rz1, rowsum(idx_s, cs, W_z, kNz, lane + 50), z1);
            }
            const unsigned long long zm0 = __ballot(z0);
            const unsigned long long zm1 = __ballot(z1);
            if (z0) idx_z[__popcll(zm0 & ((1ull << lane) - 1))] = (unsigned short)lane;
            if (z1) idx_z[__popcll(zm0) + __popcll(zm1 & ((1ull << lane) - 1))] =
                (unsigned short)(lane + 50);
            if (lane == 0) cnt_z = __popcll(zm0) + __popcll(zm1);
        } else if (wave == 4 && q == 0 && t > 0) {
            bool o0 = false, o1 = false;
            if (lane < kNs) {
                float s0 = 0.f, s1 = 0.f;
#pragma unroll
                for (int qq = 0; qq < kQN; ++qq) {
                    s0 += __hip_atomic_load(&hop[(s * kQN + qq) * kNho + lane],
                                            __ATOMIC_RELAXED, AGENT);
                    s1 += __hip_atomic_load(&hop[(s * kQN + qq) * kNho + lane + 50],
                                            __ATOMIC_RELAXED, AGENT);
                }
                lif(vo0, ro0, s0, o0);
                lif(vo1, ro1, s1, o1);
            }
            const unsigned long long om0 = __ballot(o0);
            const unsigned long long om1 = __ballot(o1);
            if (o0) idx_o[__popcll(om0 & ((1ull << lane) - 1))] = (unsigned short)lane;
            if (o1) idx_o[__popcll(om0) + __popcll(om1 & ((1ull << lane) - 1))] =
                (unsigned short)(lane + 50);
            const int co = __popcll(om0) + __popcll(om1);
            if (lane < kNout) {
                bool ys = false;
                lif(vy, ry, rowsum(idx_o, co, W_o, kNout, lane), ys);
                out[((size_t)(t - 1) * kB + b) * kNout + lane] = ys ? 1.0f : 0.0f;
            }
        }
        __syncthreads();  // sync1: idx_z ready; prevh peer fills (prev iter) ordered

        // ---- F: dense prevh @ W_h for own 128 cols, split-K 4x128 ----
        {
            const float* wh = W_h + colg;
            const int k0 = kq << 7;
            float a0 = 0.f, a1 = 0.f, a2 = 0.f, a3 = 0.f;
            for (int kb = k0; kb < k0 + 128; kb += 32) {
                float w[32];
#pragma unroll
                for (int u = 0; u < 32; ++u) w[u] = wh[(size_t)(kb + u) * kNh];
#pragma unroll
                for (int u = 0; u < 32; u += 4) {
                    const float4 p = *(const float4*)&prevh[kb + u];
                    a0 = fmaf(p.x, w[u + 0], a0);
                    a1 = fmaf(p.y, w[u + 1], a1);
                    a2 = fmaf(p.z, w[u + 2], a2);
                    a3 = fmaf(p.w, w[u + 3], a3);
                }
            }
            fpart[kq][cl] = (a0 + a1) + (a2 + a3);
        }
        __syncthreads();  // sync2

        // ---- S2 (tid<128): cz + combine + h-LIF; publish mask slice (phase A) ----
        bool hspk = false;
        if (tid < kCols) {
            czv = rowsum(idx_z, cnt_z, W_c, kNh, colg);
            const float tot = fpart[0][cl] + fpart[1][cl] + fpart[2][cl] + fpart[3][cl] + czv;
            lif(vh, rh, tot, hspk);
        }
        {
            const unsigned long long hm = __ballot(hspk);
            if (tid == 0)
                __hip_atomic_store(&masks[(s * kQN + q) * 2 + 0], hm, __ATOMIC_RELAXED, AGENT);
            if (tid == 64)
                __hip_atomic_store(&masks[(s * kQN + q) * 2 + 1], hm, __ATOMIC_RELAXED, AGENT);
        }
        __syncthreads();  // sync3: mask stores drained
        {
            const unsigned eA = kTag | (unsigned)(2 * t + 1);
            const int slot = (2 * t + 1) & 3;
            if (tid == 0) {
                __threadfence();
                __hip_atomic_store(&flags[g4 + slot], eA, __ATOMIC_RELEASE, AGENT);
            }
            if (tid < 3) {
                const int pj = (q + 1 + tid) & 3;
                while (__hip_atomic_load(&flags[(s * kQN + pj) * 4 + slot],
                                         __ATOMIC_ACQUIRE, AGENT) != eA)
                    __builtin_amdgcn_s_sleep(1);
            }
        }
        __syncthreads();  // sync4: all peer masks visible
        if (tid < 8)
            hist[t][tid] = __hip_atomic_load(&masks[(s * kQN + (tid >> 1)) * 2 + (tid & 1)],
                                             __ATOMIC_RELAXED, AGENT);
        __syncthreads();  // sync5

        // ---- S3: ck coefficients + idx_h build (full 512-bit mask) ----
        if (tid <= t) {
            int d = 0;
#pragma unroll
            for (int w = 0; w < 8; ++w) d += __popcll(hist[t][w] & hist[tid][w]);
            ck[tid] = eta * lampow[t - tid] * (float)d;
        }
        {
            const unsigned long long mw = hist[t][wave];
            if ((mw >> lane) & 1) {
                int pos = __popcll(mw & ((1ull << lane) - 1));
                for (int u = 0; u < wave; ++u) pos += __popcll(hist[t][u]);
                idx_h[pos] = (unsigned short)tid;
            }
            if (tid == 0) {
                int c = 0;
#pragma unroll
                for (int u = 0; u < 8; ++u) c += __popcll(hist[t][u]);
                cnt_h = c;
            }
        }
        __syncthreads();  // sync6

        // ---- S4: sparse h@W_h (rows split 4-way) + recall (k split 4-way) ----
        {
            const int ch = cnt_h;
            const int rlo = (ch * kq) >> 2, rhi = (ch * (kq + 1)) >> 2;
            float part = rowsum(idx_h + rlo, rhi - rlo, W_h, kNh, colg);
            const int len = t + 1;
            const int klo = (len * kq) >> 2, khi = (len * (kq + 1)) >> 2;
            const int w = colg >> 6, bit = colg & 63;
            float racc = 0.f;
            for (int k = klo; k < khi; ++k)
                racc += ((hist[k][w] >> bit) & 1) ? ck[k] : 0.f;
            spart[kq][cl] = part + racc;
        }
        __syncthreads();  // sync7

        // ---- S5 (tid<128): finalize own h_new slice; publish (phase B data 1/2) ----
        if (tid < kCols) {
            const float hn = spart[0][cl] + spart[1][cl] + spart[2][cl] + spart[3][cl] + czv;
            prevh[colg] = hn;
            __hip_atomic_store(&hnew[(s * kQN + q) * kCols + cl], hn, __ATOMIC_RELAXED, AGENT);
        }
        __syncthreads();  // sync8: own prevh slice ready for S6

        // ---- S6: own-slice W_ho partial (128 rows x 100 cols) ----
        if (tid < 500) {
            const int g = tid / kNho, c = tid - g * kNho;
            const int rl0 = (g < 3) ? 26 * g : (g == 3 ? 78 : 103);
            const int n = (g < 3) ? 26 : 25;
            const float* wp = W_ho + c;
            float s0 = 0.f, s1 = 0.f;
            int i = rl0;
            for (; i + 2 <= rl0 + n; i += 2) {
                s0 = fmaf(prevh[q * kCols + i], wp[(q * kCols + i) * kNho], s0);
                s1 = fmaf(prevh[q * kCols + i + 1], wp[(q * kCols + i + 1) * kNho], s1);
            }
            if (i < rl0 + n) s0 = fmaf(prevh[q * kCols + i], wp[(q * kCols + i) * kNho], s0);
            hored[g][c] = s0 + s1;
        }
        __syncthreads();  // sync9
        if (tid < kNho) {
            const float hv = ((hored[0][tid] + hored[1][tid]) +
                              (hored[2][tid] + hored[3][tid])) + hored[4][tid];
            __hip_atomic_store(&hop[(s * kQN + q) * kNho + tid], hv, __ATOMIC_RELAXED, AGENT);
        }
        __syncthreads();  // sync10: phase-B data drained
        {
            const unsigned eB = kTag | (unsigned)(2 * t + 2);
            const int slot = (2 * t + 2) & 3;
            if (tid == 0) {
                __threadfence();
                __hip_atomic_store(&flags[g4 + slot], eB, __ATOMIC_RELEASE, AGENT);
            }
            if (tid < 3) {
                const int pj = (q + 1 + tid) & 3;
                while (__hip_atomic_load(&flags[(s * kQN + pj) * 4 + slot],
                                         __ATOMIC_ACQUIRE, AGENT) != eB)
                    __builtin_amdgcn_s_sleep(1);
            }
        }
        __syncthreads();  // sync11: peer h_new visible
        if (tid >= 128) {
            const int pp = (tid - 128) >> 7;          // 0..2
            const int pj = (q + 1 + pp) & 3;
            const int c = tid & (kCols - 1);
            prevh[pj * kCols + c] =
                __hip_atomic_load(&hnew[(s * kQN + pj) * kCols + c], __ATOMIC_RELAXED, AGENT);
        }
        // next iteration's sync1 orders prevh fills before F
    }

    // ---- final o/y epilogue (t = kT-1): q0, wave 4 ----
    if (q == 0 && wave == 4) {
        bool o0 = false, o1 = false;
        if (lane < kNs) {
            float s0 = 0.f, s1 = 0.f;
#pragma unroll
            for (int qq = 0; qq < kQN; ++qq) {
                s0 += __hip_atomic_load(&hop[(s * kQN + qq) * kNho + lane],
                                        __ATOMIC_RELAXED, AGENT);
                s1 += __hip_atomic_load(&hop[(s * kQN + qq) * kNho + lane + 50],
                                        __ATOMIC_RELAXED, AGENT);
            }
            lif(vo0, ro0, s0, o0);
            lif(vo1, ro1, s1, o1);
        }
        const unsigned long long om0 = __ballot(o0);
        const unsigned long long om1 = __ballot(o1);
        if (o0) idx_o[__popcll(om0 & ((1ull << lane) - 1))] = (unsigned short)lane;
        if (o1) idx_o[__popcll(om0) + __popcll(om1 & ((1ull << lane) - 1))] =
            (unsigned short)(lane + 50);
        const int co = __popcll(om0) + __popcll(om1);
        if (lane < kNout) {
            bool ys = false;
            lif(vy, ry, rowsum(idx_o, co, W_o, kNout, lane), ys);
            out[((size_t)(kT - 1) * kB + b) * kNout + lane] = ys ? 1.0f : 0.0f;
        }
    }

    // ---- reset my flag slots for the next call (exact-match scheme stays valid) ----
    if (tid < 4) __hip_atomic_store(&flags[g4 + tid], 0u, __ATOMIC_RELAXED, AGENT);
}

extern "C" void kernel_launch(void* const* d_in, const int* in_sizes, int n_in,
                              void* d_out, int out_size, void* d_ws, size_t ws_size,
                              hipStream_t stream) {
    const float* x_in = (const float*)d_in[0];
    const float* W_i  = (const float*)d_in[1];
    const float* W_z  = (const float*)d_in[2];
    const float* W_c  = (const float*)d_in[3];
    const float* W_h  = (const float*)d_in[4];
    const float* W_ho = (const float*)d_in[5];
    const float* W_o  = (const float*)d_in[6];
    const float* lam  = (const float*)d_in[7];
    const float* eta  = (const float*)d_in[8];
    // workspace layout
    char* ws = (char*)d_ws;
    unsigned* flags = (unsigned*)ws;                               // 64*4*4*4   = 4096 B
    unsigned long long* masks = (unsigned long long*)(ws + 4096);  // 64*4*2*8   = 4096 B
    float* hnew = (float*)(ws + 8192);                             // 64*4*128*4 = 131072 B
    float* hop  = (float*)(ws + 8192 + 131072);                    // 64*4*100*4 = 102400 B
    snn_seq<<<kB * kQN, 512, 0, stream>>>(x_in, W_i, W_z, W_c, W_h, W_ho, W_o, lam, eta,
                                          (float*)d_out, flags, masks, hnew, hop);
}

// Round 9
// 2804.948 us; speedup vs baseline: 4.9754x; 1.9443x over previous
//
#include <hip/hip_runtime.h>
#include <stdint.h>

namespace {
constexpr int kB = 64, kT = 200;
constexpr int kNin = 700, kNs = 50, kNz = 100, kNh = 512, kNho = 100, kNout = 20;
constexpr int kQN = 4;                 // blocks per sample (h-dim split)
constexpr int kCols = kNh / kQN;       // 128 h-columns per block
constexpr int kHistW = 17;             // padded history row (u64); 8 used
constexpr int kXiW = 64;               // padded xi row stride (floats)
constexpr float kDecay = 0.95f, kThresh = 0.5f, kRefrac = 2.0f;
constexpr unsigned kTag = 0x5A5B0000u; // epoch tag (collision-proof vs 0/0xAA..)
}

#define SYS __HIP_MEMORY_SCOPE_SYSTEM

// Fence-free fabric-level exchange ops: relaxed SYSTEM-scope atomic RMWs execute
// at the cross-XCD coherence point with NO L1/L2 invalidation side effects
// (unlike acquire/release/threadfence, which emit buffer_inv/wbl2 and evict the
// L2-resident weights every step).
__device__ __forceinline__ void st_u32(unsigned* p, unsigned v) {
    (void)__hip_atomic_exchange(p, v, __ATOMIC_RELAXED, SYS);
}
__device__ __forceinline__ unsigned ld_u32(unsigned* p) {
    return __hip_atomic_fetch_add(p, 0u, __ATOMIC_RELAXED, SYS);
}
__device__ __forceinline__ void st_u64(unsigned long long* p, unsigned long long v) {
    (void)__hip_atomic_exchange(p, v, __ATOMIC_RELAXED, SYS);
}
__device__ __forceinline__ unsigned long long ld_u64(unsigned long long* p) {
    return __hip_atomic_fetch_add(p, 0ull, __ATOMIC_RELAXED, SYS);
}
__device__ __forceinline__ void st_f32(float* p, float v) {
    st_u32((unsigned*)p, __float_as_uint(v));
}
__device__ __forceinline__ float ld_f32(float* p) {
    return __uint_as_float(ld_u32((unsigned*)p));
}
__device__ __forceinline__ void drain_vmem() {
    asm volatile("s_waitcnt vmcnt(0)" ::: "memory");
}

// Adaptive-LIF update (REST=RESET=0, DT=1).
__device__ __forceinline__ void lif(float& v, float& r, float x, bool& spk) {
    r = fmaxf(r - 1.0f, 0.0f);
    v = kDecay * v + (r <= 0.0f ? x : 0.0f);
    spk = (v >= kThresh);
    if (spk) { v = 0.0f; r = kRefrac; }
}

// Deterministic sparse row-sum: sum_{i in lst[0..cnt)} W[i*ld + j]
__device__ __forceinline__ float rowsum(const unsigned short* lst, int cnt,
                                        const float* __restrict__ W, int ld, int j) {
    float a0 = 0.f, a1 = 0.f, a2 = 0.f, a3 = 0.f;
    int q = 0;
    for (; q + 4 <= cnt; q += 4) {
        const int i0 = lst[q], i1 = lst[q + 1], i2 = lst[q + 2], i3 = lst[q + 3];
        a0 += W[i0 * ld + j];
        a1 += W[i1 * ld + j];
        a2 += W[i2 * ld + j];
        a3 += W[i3 * ld + j];
    }
    for (; q < cnt; ++q) a0 += W[lst[q] * ld + j];
    return (a0 + a1) + (a2 + a3);
}

__global__ __launch_bounds__(512, 1)
void snn_seq(const float* __restrict__ x_in, const float* __restrict__ W_i,
             const float* __restrict__ W_z, const float* __restrict__ W_c,
             const float* __restrict__ W_h, const float* __restrict__ W_ho,
             const float* __restrict__ W_o, const float* __restrict__ lam_p,
             const float* __restrict__ eta_p, float* __restrict__ out,
             unsigned* __restrict__ flags, unsigned long long* __restrict__ masks,
             float* __restrict__ hnew, float* __restrict__ hop) {
    __shared__ unsigned long long hist[kT][kHistW];     // 27200 B (full 512-bit hist)
    __shared__ float xi[kT * kXiW];                     // 51200 B
    __shared__ float lampow[kT];                        // 800
    __shared__ float ck[kT];                            // 800
    __shared__ __align__(16) float prevh[kNh];          // 2048 (full h_new)
    __shared__ float fpart[kQN][kCols];                 // 2048
    __shared__ float spart[kQN][kCols];                 // 2048
    __shared__ float hored[5][kNho];                    // 2000
    __shared__ unsigned short idx_s[kNs], idx_z[kNz], idx_h[kNh], idx_o[kNho];
    __shared__ int cnt_z, cnt_h;

    const int tid = threadIdx.x;
    const int lane = tid & 63;
    const int wave = tid >> 6;            // 0..7
    const int s = blockIdx.x & 63;        // sample
    const int q = blockIdx.x >> 6;        // h-slice 0..3 (group {s,s+64,s+128,s+192})
    const int cl = tid & (kCols - 1);     // column within slice
    const int kq = tid >> 7;              // K-quarter / row-quarter
    const int colg = q * kCols + cl;      // global h column
    const int g4 = (s * kQN + q) * 4;     // my flag base
    const int b = s;
    const float lam = lam_p[0], eta = eta_p[0];

    // ---- prologue: lampow, prevh=0, xi = x@W_i for all t (replicated per block) ----
    if (tid == 0) {
        float p = 1.0f;
        for (int i = 0; i < kT; ++i) { lampow[i] = p; p *= lam; }
    }
    prevh[tid] = 0.0f;
    if (tid < 500) {
        const int jj = tid % kNs;
        const int tslot = tid / kNs;      // 0..9
        const float* wcol = W_i + jj;
        const size_t str10 = (size_t)10 * kB * kNin;
        for (int p = 0; p < 5; ++p) {
            const int tb = tslot + 40 * p;
            const float* x0 = x_in + ((size_t)tb * kB + b) * kNin;
            float a0 = 0.f, a1 = 0.f, a2 = 0.f, a3 = 0.f;
            for (int i = 0; i < kNin; ++i) {
                const float w = wcol[i * kNs];
                a0 = fmaf(x0[i], w, a0);
                a1 = fmaf(x0[str10 + i], w, a1);
                a2 = fmaf(x0[2 * str10 + i], w, a2);
                a3 = fmaf(x0[3 * str10 + i], w, a3);
            }
            xi[(tb + 0) * kXiW + jj] = a0;
            xi[(tb + 10) * kXiW + jj] = a1;
            xi[(tb + 20) * kXiW + jj] = a2;
            xi[(tb + 30) * kXiW + jj] = a3;
        }
    }

    // LIF states (owner lanes only)
    float vs = 0, rs = 0, vz0 = 0, rz0 = 0, vz1 = 0, rz1 = 0;   // wave 0, replicated
    float vo0 = 0, ro0 = 0, vo1 = 0, ro1 = 0, vy = 0, ry = 0;   // q0, wave 4
    float vh = 0, rh = 0, czv = 0;                              // tid<128 (own slice)

    __syncthreads();

    for (int t = 0; t < kT; ++t) {
        // ---- P0: wave0 = s/z (replicated); q0-wave4 = o/y epilogue of t-1 ----
        if (wave == 0) {
            bool sspk = false;
            if (lane < kNs) lif(vs, rs, xi[t * kXiW + lane], sspk);
            const unsigned long long sm = __ballot(sspk);
            if (sspk) idx_s[__popcll(sm & ((1ull << lane) - 1))] = (unsigned short)lane;
            const int cs = __popcll(sm);
            bool z0 = false, z1 = false;
            if (lane < kNs) {
                lif(vz0, rz0, rowsum(idx_s, cs, W_z, kNz, lane), z0);
                lif(vz1, rz1, rowsum(idx_s, cs, W_z, kNz, lane + 50), z1);
            }
            const unsigned long long zm0 = __ballot(z0);
            const unsigned long long zm1 = __ballot(z1);
            if (z0) idx_z[__popcll(zm0 & ((1ull << lane) - 1))] = (unsigned short)lane;
            if (z1) idx_z[__popcll(zm0) + __popcll(zm1 & ((1ull << lane) - 1))] =
                (unsigned short)(lane + 50);
            if (lane == 0) cnt_z = __popcll(zm0) + __popcll(zm1);
        } else if (wave == 4 && q == 0 && t > 0) {
            bool o0 = false, o1 = false;
            if (lane < kNs) {
                float s0 = 0.f, s1 = 0.f;
#pragma unroll
                for (int qq = 0; qq < kQN; ++qq) {
                    s0 += ld_f32(&hop[(s * kQN + qq) * kNho + lane]);
                    s1 += ld_f32(&hop[(s * kQN + qq) * kNho + lane + 50]);
                }
                lif(vo0, ro0, s0, o0);
                lif(vo1, ro1, s1, o1);
            }
            const unsigned long long om0 = __ballot(o0);
            const unsigned long long om1 = __ballot(o1);
            if (o0) idx_o[__popcll(om0 & ((1ull << lane) - 1))] = (unsigned short)lane;
            if (o1) idx_o[__popcll(om0) + __popcll(om1 & ((1ull << lane) - 1))] =
                (unsigned short)(lane + 50);
            const int co = __popcll(om0) + __popcll(om1);
            if (lane < kNout) {
                bool ys = false;
                lif(vy, ry, rowsum(idx_o, co, W_o, kNout, lane), ys);
                out[((size_t)(t - 1) * kB + b) * kNout + lane] = ys ? 1.0f : 0.0f;
            }
        }
        __syncthreads();  // sync1: idx_z ready; prevh peer fills (prev iter) ordered

        // ---- F: dense prevh @ W_h for own 128 cols, split-K 4x128 ----
        {
            const float* wh = W_h + colg;
            const int k0 = kq << 7;
            float a0 = 0.f, a1 = 0.f, a2 = 0.f, a3 = 0.f;
            for (int kb = k0; kb < k0 + 128; kb += 32) {
                float w[32];
#pragma unroll
                for (int u = 0; u < 32; ++u) w[u] = wh[(size_t)(kb + u) * kNh];
#pragma unroll
                for (int u = 0; u < 32; u += 4) {
                    const float4 p = *(const float4*)&prevh[kb + u];
                    a0 = fmaf(p.x, w[u + 0], a0);
                    a1 = fmaf(p.y, w[u + 1], a1);
                    a2 = fmaf(p.z, w[u + 2], a2);
                    a3 = fmaf(p.w, w[u + 3], a3);
                }
            }
            fpart[kq][cl] = (a0 + a1) + (a2 + a3);
        }
        __syncthreads();  // sync2

        // ---- S2 (tid<128): cz + combine + h-LIF; publish mask slice (phase A) ----
        bool hspk = false;
        if (tid < kCols) {
            czv = rowsum(idx_z, cnt_z, W_c, kNh, colg);
            const float tot = fpart[0][cl] + fpart[1][cl] + fpart[2][cl] + fpart[3][cl] + czv;
            lif(vh, rh, tot, hspk);
        }
        {
            const unsigned long long hm = __ballot(hspk);
            if (tid == 0) st_u64(&masks[(s * kQN + q) * 2 + 0], hm);
            if (tid == 64) st_u64(&masks[(s * kQN + q) * 2 + 1], hm);
        }
        __syncthreads();  // sync3: mask swaps issued by tid 0/64
        {
            const unsigned eA = kTag | (unsigned)(2 * t + 1);
            const int slot = (2 * t + 1) & 3;
            if (tid == 0) {
                drain_vmem();                       // masks complete before flag
                st_u32(&flags[g4 + slot], eA);
            }
            if (tid < 3) {
                const int pj = (q + 1 + tid) & 3;
                while (ld_u32(&flags[(s * kQN + pj) * 4 + slot]) != eA)
                    __builtin_amdgcn_s_sleep(2);
            }
        }
        __syncthreads();  // sync4: all peer masks visible
        if (tid < 8)
            hist[t][tid] = ld_u64(&masks[(s * kQN + (tid >> 1)) * 2 + (tid & 1)]);
        __syncthreads();  // sync5

        // ---- S3: ck coefficients + idx_h build (full 512-bit mask) ----
        if (tid <= t) {
            int d = 0;
#pragma unroll
            for (int w = 0; w < 8; ++w) d += __popcll(hist[t][w] & hist[tid][w]);
            ck[tid] = eta * lampow[t - tid] * (float)d;
        }
        {
            const unsigned long long mw = hist[t][wave];
            if ((mw >> lane) & 1) {
                int pos = __popcll(mw & ((1ull << lane) - 1));
                for (int u = 0; u < wave; ++u) pos += __popcll(hist[t][u]);
                idx_h[pos] = (unsigned short)tid;
            }
            if (tid == 0) {
                int c = 0;
#pragma unroll
                for (int u = 0; u < 8; ++u) c += __popcll(hist[t][u]);
                cnt_h = c;
            }
        }
        __syncthreads();  // sync6

        // ---- S4: sparse h@W_h (rows split 4-way) + recall (k split 4-way) ----
        {
            const int ch = cnt_h;
            const int rlo = (ch * kq) >> 2, rhi = (ch * (kq + 1)) >> 2;
            float part = rowsum(idx_h + rlo, rhi - rlo, W_h, kNh, colg);
            const int len = t + 1;
            const int klo = (len * kq) >> 2, khi = (len * (kq + 1)) >> 2;
            const int w = colg >> 6, bit = colg & 63;
            float racc = 0.f;
            for (int k = klo; k < khi; ++k)
                racc += ((hist[k][w] >> bit) & 1) ? ck[k] : 0.f;
            spart[kq][cl] = part + racc;
        }
        __syncthreads();  // sync7

        // ---- S5 (tid<128): finalize own h_new slice; publish (phase B data 1/2) ----
        if (tid < kCols) {
            const float hn = spart[0][cl] + spart[1][cl] + spart[2][cl] + spart[3][cl] + czv;
            prevh[colg] = hn;
            st_f32(&hnew[(s * kQN + q) * kCols + cl], hn);
        }
        __syncthreads();  // sync8: own prevh slice ready for S6

        // ---- S6: own-slice W_ho partial (128 rows x 100 cols) ----
        if (tid < 500) {
            const int g = tid / kNho, c = tid - g * kNho;
            const int rl0 = (g < 3) ? 26 * g : (g == 3 ? 78 : 103);
            const int n = (g < 3) ? 26 : 25;
            const float* wp = W_ho + c;
            float s0 = 0.f, s1 = 0.f;
            int i = rl0;
            for (; i + 2 <= rl0 + n; i += 2) {
                s0 = fmaf(prevh[q * kCols + i], wp[(q * kCols + i) * kNho], s0);
                s1 = fmaf(prevh[q * kCols + i + 1], wp[(q * kCols + i + 1) * kNho], s1);
            }
            if (i < rl0 + n) s0 = fmaf(prevh[q * kCols + i], wp[(q * kCols + i) * kNho], s0);
            hored[g][c] = s0 + s1;
        }
        __syncthreads();  // sync9
        if (tid < kNho) {
            const float hv = ((hored[0][tid] + hored[1][tid]) +
                              (hored[2][tid] + hored[3][tid])) + hored[4][tid];
            st_f32(&hop[(s * kQN + q) * kNho + tid], hv);
        }
        __syncthreads();  // sync10: phase-B data swaps issued
        {
            const unsigned eB = kTag | (unsigned)(2 * t + 2);
            const int slot = (2 * t + 2) & 3;
            if (tid == 0) {
                drain_vmem();                       // hnew+hop complete before flag
                st_u32(&flags[g4 + slot], eB);
            }
            if (tid < 3) {
                const int pj = (q + 1 + tid) & 3;
                while (ld_u32(&flags[(s * kQN + pj) * 4 + slot]) != eB)
                    __builtin_amdgcn_s_sleep(2);
            }
        }
        __syncthreads();  // sync11: peer h_new visible
        if (tid >= 128) {
            const int pp = (tid - 128) >> 7;          // 0..2
            const int pj = (q + 1 + pp) & 3;
            const int c = tid & (kCols - 1);
            prevh[pj * kCols + c] = ld_f32(&hnew[(s * kQN + pj) * kCols + c]);
        }
        // next iteration's sync1 orders prevh fills before F
    }

    // ---- final o/y epilogue (t = kT-1): q0, wave 4 ----
    if (q == 0 && wave == 4) {
        bool o0 = false, o1 = false;
        if (lane < kNs) {
            float s0 = 0.f, s1 = 0.f;
#pragma unroll
            for (int qq = 0; qq < kQN; ++qq) {
                s0 += ld_f32(&hop[(s * kQN + qq) * kNho + lane]);
                s1 += ld_f32(&hop[(s * kQN + qq) * kNho + lane + 50]);
            }
            lif(vo0, ro0, s0, o0);
            lif(vo1, ro1, s1, o1);
        }
        const unsigned long long om0 = __ballot(o0);
        const unsigned long long om1 = __ballot(o1);
        if (o0) idx_o[__popcll(om0 & ((1ull << lane) - 1))] = (unsigned short)lane;
        if (o1) idx_o[__popcll(om0) + __popcll(om1 & ((1ull << lane) - 1))] =
            (unsigned short)(lane + 50);
        const int co = __popcll(om0) + __popcll(om1);
        if (lane < kNout) {
            bool ys = false;
            lif(vy, ry, rowsum(idx_o, co, W_o, kNout, lane), ys);
            out[((size_t)(kT - 1) * kB + b) * kNout + lane] = ys ? 1.0f : 0.0f;
        }
    }

    // ---- reset my flag slots for the next call (exact-match scheme stays valid) ----
    if (tid < 4) st_u32(&flags[g4 + tid], 0u);
}

extern "C" void kernel_launch(void* const* d_in, const int* in_sizes, int n_in,
                              void* d_out, int out_size, void* d_ws, size_t ws_size,
                              hipStream_t stream) {
    const float* x_in = (const float*)d_in[0];
    const float* W_i  = (const float*)d_in[1];
    const float* W_z  = (const float*)d_in[2];
    const float* W_c  = (const float*)d_in[3];
    const float* W_h  = (const float*)d_in[4];
    const float* W_ho = (const float*)d_in[5];
    const float* W_o  = (const float*)d_in[6];
    const float* lam  = (const float*)d_in[7];
    const float* eta  = (const float*)d_in[8];
    // workspace layout
    char* ws = (char*)d_ws;
    unsigned* flags = (unsigned*)ws;                               // 64*4*4*4   = 4096 B
    unsigned long long* masks = (unsigned long long*)(ws + 4096);  // 64*4*2*8   = 4096 B
    float* hnew = (float*)(ws + 8192);                             // 64*4*128*4 = 131072 B
    float* hop  = (float*)(ws + 8192 + 131072);                    // 64*4*100*4 = 102400 B
    snn_seq<<<kB * kQN, 512, 0, stream>>>(x_in, W_i, W_z, W_c, W_h, W_ho, W_o, lam, eta,
                                          (float*)d_out, flags, masks, hnew, hop);
}